// Round 2
// baseline (2808.972 us; speedup 1.0000x reference)
//
#include <hip/hip_runtime.h>
#include <stdint.h>

typedef unsigned int u32;
typedef unsigned long long u64;

#define HF 96
#define HW 9216           // 96*96
#define CIN 1024
#define CMID 512
#define NA 82944          // HW*9
#define PRE 12000
#define POST 300
#define NW 188            // ceil(PRE/64)
#define NBLK 324          // NA/256
#define OUT_POOL (POST*CIN*49)

// base anchors, exact per np.round (banker's) of the reference generator:
// ws=round(sqrt(256/ratio))={23,16,11}; hs=round(ws*ratio)={12,16,22}; ctr 7.5
__device__ __constant__ float BA[9][4] = {
  {-84.f,-40.f,99.f,55.f}, {-176.f,-88.f,191.f,103.f}, {-360.f,-184.f,375.f,199.f},
  {-56.f,-56.f,71.f,71.f}, {-120.f,-120.f,135.f,135.f}, {-248.f,-248.f,263.f,263.f},
  {-36.f,-80.f,51.f,95.f}, {-80.f,-168.f,95.f,183.f},  {-168.f,-344.f,183.f,359.f}
};

__device__ __forceinline__ u32 fkey(float f) {
  u32 u = __float_as_uint(f);
  return (u & 0x80000000u) ? ~u : (u | 0x80000000u);
}

// ---------------- K1: 3x3 conv 1024->512 + bias + ReLU ----------------
// grid (8 co-groups, 32 y-groups), 512 threads. tile: 64 co x 3 y x 96 x.
#define CK 8
__global__ __launch_bounds__(512) void rpn_conv3(
    const float* __restrict__ feat, const float* __restrict__ w,
    const float* __restrict__ b, float* __restrict__ out)
{
  __shared__ float in_s[CK][5][98];
  __shared__ float w_s[CK][64][12];
  const int co0 = blockIdx.x * 64;
  const int y0  = blockIdx.y * 3;
  const int tid = threadIdx.x;
  const int t_x  = tid & 31;
  const int t_co = tid >> 5;   // 0..15
  float acc[4][3][3];
#pragma unroll
  for (int j=0;j<4;j++)
#pragma unroll
    for (int py=0;py<3;py++)
#pragma unroll
      for (int g=0;g<3;g++) acc[j][py][g]=0.f;

  for (int ci0 = 0; ci0 < CIN; ci0 += CK) {
    for (int idx = tid; idx < CK*5*98; idx += 512) {
      int ci  = idx / (5*98);
      int rem = idx - ci*5*98;
      int row = rem / 98;
      int col = rem - row*98;
      int gy = y0 - 1 + row;
      int gx = col - 1;
      float v = 0.f;
      if ((unsigned)gy < 96u && (unsigned)gx < 96u)
        v = feat[(ci0+ci)*HW + gy*96 + gx];
      in_s[ci][row][col] = v;
    }
    for (int idx = tid; idx < 64*CK*9; idx += 512) {
      int co  = idx / 72;
      int rem = idx - co*72;
      int ci  = rem / 9;
      int k   = rem - ci*9;
      w_s[ci][co][k] = w[((co0+co)*CIN + ci0+ci)*9 + k];
    }
    __syncthreads();
#pragma unroll
    for (int ci=0; ci<CK; ++ci) {
      float wv[4][9];
#pragma unroll
      for (int j=0;j<4;j++) {
        const float4 wa = *(const float4*)&w_s[ci][t_co*4+j][0];
        const float4 wb = *(const float4*)&w_s[ci][t_co*4+j][4];
        wv[j][0]=wa.x; wv[j][1]=wa.y; wv[j][2]=wa.z; wv[j][3]=wa.w;
        wv[j][4]=wb.x; wv[j][5]=wb.y; wv[j][6]=wb.z; wv[j][7]=wb.w;
        wv[j][8]=w_s[ci][t_co*4+j][8];
      }
#pragma unroll
      for (int g=0; g<3; ++g) {
        const int x = t_x + g*32;
#pragma unroll
        for (int r=0; r<5; ++r) {
          const float i0 = in_s[ci][r][x];
          const float i1 = in_s[ci][r][x+1];
          const float i2 = in_s[ci][r][x+2];
#pragma unroll
          for (int py=0; py<3; ++py) {
            const int ky = r - py;          // input row r serves output py with ky
            if (ky < 0 || ky > 2) continue;
#pragma unroll
            for (int j=0;j<4;j++) {
              acc[j][py][g] = fmaf(i0, wv[j][ky*3+0], acc[j][py][g]);
              acc[j][py][g] = fmaf(i1, wv[j][ky*3+1], acc[j][py][g]);
              acc[j][py][g] = fmaf(i2, wv[j][ky*3+2], acc[j][py][g]);
            }
          }
        }
      }
    }
    __syncthreads();
  }
#pragma unroll
  for (int j=0;j<4;j++) {
    const int co = co0 + t_co*4 + j;
    const float bb = b[co];
#pragma unroll
    for (int py=0;py<3;py++)
#pragma unroll
      for (int g=0;g<3;g++) {
        float v = acc[j][py][g] + bb;
        out[co*HW + (y0+py)*96 + t_x + g*32] = v > 0.f ? v : 0.f;
      }
  }
}

// ---------------- K2: 1x1 convs (cls 18 + bbox 36) ----------------
__global__ void conv1x1(const float* __restrict__ rpn,
    const float* __restrict__ cw, const float* __restrict__ cb,
    const float* __restrict__ bw, const float* __restrict__ bb,
    float* __restrict__ cls_out, float* __restrict__ bbox_out)
{
  const int hw = blockIdx.x * 64 + threadIdx.x;
  float accA[18], accB[36];
#pragma unroll
  for (int c=0;c<18;c++) accA[c]=0.f;
#pragma unroll
  for (int c=0;c<36;c++) accB[c]=0.f;
  for (int ci=0; ci<CMID; ++ci) {
    const float v = rpn[ci*HW + hw];
#pragma unroll
    for (int c=0;c<18;c++) accA[c] = fmaf(v, cw[c*CMID+ci], accA[c]);
#pragma unroll
    for (int c=0;c<36;c++) accB[c] = fmaf(v, bw[c*CMID+ci], accB[c]);
  }
#pragma unroll
  for (int c=0;c<18;c++) cls_out[c*HW+hw] = accA[c] + cb[c];
#pragma unroll
  for (int c=0;c<36;c++) bbox_out[c*HW+hw] = accB[c] + bb[c];
}

// ---------------- K3: scores (softmax fg), keys, histogram, decode+clip ----------------
__global__ void score_decode(const float* __restrict__ cls_out,
    const float* __restrict__ bbox_out, const float* __restrict__ im_info,
    u64* __restrict__ keys, float4* __restrict__ props, u32* __restrict__ hist)
{
#pragma clang fp contract(off)
  const int n = blockIdx.x*256 + threadIdx.x;
  const int hw = n / 9;
  const int a  = n - hw*9;
  const int x = hw % HF, y = hw / HF;
  const float l0 = cls_out[a*HW + hw];
  const float l1 = cls_out[(9+a)*HW + hw];
  const float m = fmaxf(l0, l1);
  const float e0 = expf(l0 - m), e1 = expf(l1 - m);
  const float s = e1 / (e0 + e1);
  const u32 sb = __float_as_uint(s);      // s >= 0 -> bits monotone
  keys[n] = ((u64)(~sb) << 32) | (u32)n;  // asc key == desc score, tie -> asc idx
  atomicAdd(&hist[sb >> 16], 1u);

  const float ax1 = BA[a][0] + 16.f*(float)x;
  const float ay1 = BA[a][1] + 16.f*(float)y;
  const float ax2 = BA[a][2] + 16.f*(float)x;
  const float ay2 = BA[a][3] + 16.f*(float)y;
  const float aw = ax2 - ax1 + 1.f, ah = ay2 - ay1 + 1.f;
  const float cx = ax1 + 0.5f*aw,  cy = ay1 + 0.5f*ah;
  const float d0 = bbox_out[(a*4+0)*HW + hw];
  const float d1 = bbox_out[(a*4+1)*HW + hw];
  const float d2 = bbox_out[(a*4+2)*HW + hw];
  const float d3 = bbox_out[(a*4+3)*HW + hw];
  const float pcx = d0*aw + cx, pcy = d1*ah + cy;
  const float pw = expf(d2)*aw, ph = expf(d3)*ah;
  const float imh = im_info[0], imw = im_info[1];
  float bx1 = fminf(fmaxf(pcx - 0.5f*pw, 0.f), imw - 1.f);
  float by1 = fminf(fmaxf(pcy - 0.5f*ph, 0.f), imh - 1.f);
  float bx2 = fminf(fmaxf(pcx + 0.5f*pw, 0.f), imw - 1.f);
  float by2 = fminf(fmaxf(pcy + 0.5f*ph, 0.f), imh - 1.f);
  props[n] = make_float4(bx1, by1, bx2, by2);
}

// ---------------- K4: find threshold bucket (count(bucket>=t) >= PRE) ----------------
__global__ void hist_scan(const u32* __restrict__ hist, u32* __restrict__ thresh)
{
  __shared__ u32 csum[1024];
  const int t = threadIdx.x;
  u32 s = 0;
  for (int i=0;i<64;i++) s += hist[t*64+i];
  csum[t] = s;
  __syncthreads();
  if (t == 0) {
    u32 cum = 0;
    int tc = 1023;
    for (; tc >= 0; --tc) {
      if (cum + csum[tc] >= PRE) break;
      cum += csum[tc];
    }
    u32 b = (u32)tc*64u + 63u;
    for (;;) { cum += hist[b]; if (cum >= PRE) break; --b; }
    thresh[0] = b;
  }
}

// ---------------- K5: compact candidates ----------------
__global__ void collect_cand(const u64* __restrict__ keys, const u32* __restrict__ thresh,
                             u32* __restrict__ counter, u64* __restrict__ cand)
{
  const int n = blockIdx.x*256 + threadIdx.x;
  const u64 k = keys[n];
  const u32 sb = ~(u32)(k >> 32);
  if ((sb >> 16) >= thresh[0]) {
    u32 p = atomicAdd(counter, 1u);
    cand[p] = k;
  }
}

// ---------------- K6: exact rank among candidates -> scatter sorted boxes ----------------
__global__ void rank_scatter(const u64* __restrict__ cand, const u32* __restrict__ counter,
                             const float4* __restrict__ props, float4* __restrict__ sprops)
{
  __shared__ u64 sk[256];
  const int M = (int)counter[0];
  if (blockIdx.x*256 >= M) return;        // block-uniform
  const int i = blockIdx.x*256 + threadIdx.x;
  const u64 key = (i < M) ? cand[i] : ~0ull;
  int rank = 0;
  for (int t0 = 0; t0 < M; t0 += 256) {
    const int j = t0 + threadIdx.x;
    sk[threadIdx.x] = (j < M) ? cand[j] : ~0ull;
    __syncthreads();
#pragma unroll 8
    for (int k=0;k<256;k++) rank += (sk[k] < key) ? 1 : 0;
    __syncthreads();
  }
  if (i < M && rank < PRE) sprops[rank] = props[(u32)key];
}

// ---------------- K7: NMS suppression bitmask ----------------
__global__ void nms_mask(const float4* __restrict__ sp, u64* __restrict__ mask)
{
#pragma clang fp contract(off)
  __shared__ float4 cb[64];
  __shared__ float  ca[64];
  const int c0 = blockIdx.x * 64;
  const int cend = min(64, PRE - c0);
  if ((int)threadIdx.x < cend) {
    float4 b = sp[c0 + threadIdx.x];
    cb[threadIdx.x] = b;
    ca[threadIdx.x] = (b.z-b.x+1.f)*(b.w-b.y+1.f);
  }
  __syncthreads();
  const int row = blockIdx.y*64 + threadIdx.x;
  if (row >= PRE) return;
  const float4 rb = sp[row];
  const float ra = (rb.z-rb.x+1.f)*(rb.w-rb.y+1.f);
  u64 bits = 0;
  for (int j=0;j<cend;j++) {
    const float4 c = cb[j];
    const float xx1 = fmaxf(rb.x, c.x), yy1 = fmaxf(rb.y, c.y);
    const float xx2 = fminf(rb.z, c.z), yy2 = fminf(rb.w, c.w);
    const float inter = fmaxf(xx2-xx1+1.f, 0.f) * fmaxf(yy2-yy1+1.f, 0.f);
    const float iou = inter / (ra + ca[j] - inter);
    if (iou > 0.7f) bits |= (1ull << j);
  }
  mask[(size_t)row*NW + blockIdx.x] = bits;
}

// ---------------- K8: serial greedy scan (one wave) -> rois ----------------
__global__ void nms_scan(const u64* __restrict__ mask, const float4* __restrict__ sp,
                         float* __restrict__ rois)
{
  __shared__ int keep_s[POST];
  const int l = threadIdx.x;               // 0..63, lane l owns words 3l..3l+2
  u64 v[3];
#pragma unroll
  for (int q=0;q<3;q++) {
    const int w = l*3+q;
    u64 val = 0;
    if (w < NW) { val = ~0ull; if (w == NW-1) val = (1ull<<32) - 1ull; }
    v[q] = val;
  }
  for (int it=0; it<POST; ++it) {
    const u64 nz = v[0] | v[1] | v[2];
    const u64 bal = __ballot(nz != 0);
    int idx;
    if (bal == 0) idx = -1;
    else {
      const int src = __ffsll((unsigned long long)bal) - 1;
      int fi = 0;
      if (v[0])      fi = (l*3+0)*64 + __ffsll(v[0]) - 1;
      else if (v[1]) fi = (l*3+1)*64 + __ffsll(v[1]) - 1;
      else if (v[2]) fi = (l*3+2)*64 + __ffsll(v[2]) - 1;
      idx = __shfl(fi, src);
    }
    if (l == 0) keep_s[it] = (idx < 0) ? 0 : idx;
    if (idx >= 0) {
      const u64* mrow = mask + (size_t)idx*NW;
#pragma unroll
      for (int q=0;q<3;q++) {
        const int w = l*3+q;
        if (w < NW) v[q] &= ~mrow[w];
      }
    }
  }
  __syncthreads();
  for (int i = l; i < POST; i += 64) {
    const float4 b = sp[keep_s[i]];
    rois[i*5+0] = 0.f;
    rois[i*5+1] = b.x; rois[i*5+2] = b.y; rois[i*5+3] = b.z; rois[i*5+4] = b.w;
  }
}

// ---------------- K9/K10: ROI bilinear crop ----------------
struct __align__(16) Samp { int p0,p1,p2,p3; float w0,w1,w2,w3; };

__global__ void roi_table(const float* __restrict__ rois, Samp* __restrict__ tab)
{
#pragma clang fp contract(off)
  const int idx = blockIdx.x*256 + threadIdx.x;
  if (idx >= POST*49) return;
  const int r = idx / 49;
  const int s = idx - r*49;
  const int py = s / 7, px = s - py*7;
  const float x1 = rois[r*5+1] * 0.0625f;
  const float y1 = rois[r*5+2] * 0.0625f;
  const float x2 = rois[r*5+3] * 0.0625f;
  const float y2 = rois[r*5+4] * 0.0625f;
  const float t00 = (x2-x1)/95.f;
  const float t02 = (x1+x2-95.f)/95.f;
  const float t11 = (y2-y1)/95.f;
  const float t12 = (y1+y2-95.f)/95.f;
  const float lx = (float)(px-3)/3.f;
  const float ly = (float)(py-3)/3.f;
  const float gx = t00*lx + t02;
  const float gy = t11*ly + t12;
  const float ix = (gx+1.f)*0.5f*95.f;
  const float iy = (gy+1.f)*0.5f*95.f;
  const float ix0 = floorf(ix), iy0 = floorf(iy);
  const float wx = ix-ix0, wy = iy-iy0;
  const float xs[2] = {ix0, ix0+1.f};
  const float ys[2] = {iy0, iy0+1.f};
  const float wxs[2] = {1.f-wx, wx};
  const float wys[2] = {1.f-wy, wy};
  int pos[4]; float wt[4];
#pragma unroll
  for (int k=0;k<4;k++) {
    const int dy = k>>1, dx = k&1;
    const float yi = ys[dy], xi = xs[dx];
    const bool valid = (yi>=0.f)&&(yi<96.f)&&(xi>=0.f)&&(xi<96.f);
    const int yc = (int)fminf(fmaxf(yi,0.f),95.f);
    const int xc = (int)fminf(fmaxf(xi,0.f),95.f);
    pos[k] = yc*96+xc;
    wt[k] = wys[dy]*wxs[dx] * (valid?1.f:0.f);
  }
  Samp t;
  t.p0=pos[0]; t.p1=pos[1]; t.p2=pos[2]; t.p3=pos[3];
  t.w0=wt[0];  t.w1=wt[1];  t.w2=wt[2];  t.w3=wt[3];
  tab[idx] = t;
}

__global__ void roi_pool(const float* __restrict__ feat, const Samp* __restrict__ tab,
                         float* __restrict__ out)
{
#pragma clang fp contract(off)
  const int o = blockIdx.x*256 + threadIdx.x;   // grid exact: OUT_POOL/256
  const int s  = o % 49;
  const int rc = o / 49;
  const int c = rc & (CIN-1);
  const int r = rc >> 10;
  const Samp t = tab[r*49+s];
  const float* f = feat + (size_t)c*HW;
  out[o] = t.w0*f[t.p0] + t.w1*f[t.p1] + t.w2*f[t.p2] + t.w3*f[t.p3];
}

// ---------------- K11: anchor-gt IoU matrix (masked) + per-gt max ----------------
__global__ void anchor_ov(const float* __restrict__ gt, const float* __restrict__ im_info,
                          float* __restrict__ ov, u32* __restrict__ gtmax)
{
#pragma clang fp contract(off)
  __shared__ u32 lmax[8];
  if (threadIdx.x < 8) lmax[threadIdx.x] = 0u;
  __syncthreads();
  const int n = blockIdx.x*256 + threadIdx.x;
  const int hw = n/9, a = n - hw*9;
  const int x = hw % HF, y = hw / HF;
  const float ax1 = BA[a][0]+16.f*(float)x, ay1 = BA[a][1]+16.f*(float)y;
  const float ax2 = BA[a][2]+16.f*(float)x, ay2 = BA[a][3]+16.f*(float)y;
  const float imh = im_info[0], imw = im_info[1];
  const bool inside = (ax1 >= 0.f) && (ay1 >= 0.f) && (ax2 < imw) && (ay2 < imh);
  const float aa = (ax2-ax1+1.f)*(ay2-ay1+1.f);
#pragma unroll
  for (int j=0;j<8;j++) {
    const float g0=gt[j*5+0], g1=gt[j*5+1], g2=gt[j*5+2], g3=gt[j*5+3];
    const float ga = (g2-g0+1.f)*(g3-g1+1.f);
    const float xx1 = fmaxf(ax1,g0), yy1 = fmaxf(ay1,g1);
    const float xx2 = fminf(ax2,g2), yy2 = fminf(ay2,g3);
    const float inter = fmaxf(xx2-xx1+1.f,0.f)*fmaxf(yy2-yy1+1.f,0.f);
    const float iou = inter/(aa+ga-inter);
    const float o = inside ? iou : -1.f;
    ov[(size_t)n*8+j] = o;
    atomicMax(&lmax[j], fkey(o));
  }
  __syncthreads();
  if (threadIdx.x < 8) atomicMax(&gtmax[threadIdx.x], lmax[threadIdx.x]);
}

// ---------------- K12: labels + argmax + ex-count partials ----------------
__global__ void anchor_label(const float* __restrict__ ov, const u32* __restrict__ gtmax,
                             signed char* __restrict__ labels, signed char* __restrict__ amax,
                             int* __restrict__ exP)
{
  __shared__ int se[256];
  const int n = blockIdx.x*256 + threadIdx.x;
  float best = -3.402823466e38f;
  int arg = 0;
  bool isbest = false;
#pragma unroll
  for (int j=0;j<8;j++) {
    const float o = ov[(size_t)n*8+j];
    if (o > best) { best = o; arg = j; }
    if (fkey(o) == gtmax[j]) isbest = true;
  }
  const bool inside = ov[(size_t)n*8+0] >= 0.f;
  int lab = -1;
  if (inside && best < 0.3f) lab = 0;
  if (inside && isbest) lab = 1;
  if (inside && best >= 0.7f) lab = 1;
  labels[n] = (signed char)lab;
  amax[n] = (signed char)arg;
  se[threadIdx.x] = (lab >= 0) ? 1 : 0;
  __syncthreads();
  for (int s=128; s>0; s>>=1) {
    if ((int)threadIdx.x < s) se[threadIdx.x] += se[threadIdx.x+s];
    __syncthreads();
  }
  if (threadIdx.x==0) exP[blockIdx.x] = se[0];
}

// ---------------- K13: per-anchor loss terms -> block partials ----------------
__global__ void loss_partial(const float* __restrict__ cls_out, const float* __restrict__ bbox_out,
                             const float* __restrict__ gt, const signed char* __restrict__ labels,
                             const signed char* __restrict__ amax, float2* __restrict__ lossP)
{
#pragma clang fp contract(off)
  __shared__ float sce[256];
  __shared__ float sbx[256];
  const int n = blockIdx.x*256 + threadIdx.x;
  const int hw = n/9, a = n - hw*9;
  const int lab = labels[n];
  float ce = 0.f, bx = 0.f;
  if (lab >= 0) {
    const float l0 = cls_out[a*HW+hw], l1 = cls_out[(9+a)*HW+hw];
    const float m = fmaxf(l0,l1);
    const float lse = m + logf(expf(l0-m)+expf(l1-m));
    ce = lse - (lab==1 ? l1 : l0);
  }
  if (lab == 1) {
    const int x = hw % HF, y = hw / HF;
    const float ax1 = BA[a][0]+16.f*(float)x, ay1 = BA[a][1]+16.f*(float)y;
    const float ax2 = BA[a][2]+16.f*(float)x, ay2 = BA[a][3]+16.f*(float)y;
    const float ew = ax2-ax1+1.f, eh = ay2-ay1+1.f;
    const float ecx = ax1+0.5f*ew, ecy = ay1+0.5f*eh;
    const int g = amax[n];
    const float g0=gt[g*5+0], g1=gt[g*5+1], g2=gt[g*5+2], g3=gt[g*5+3];
    const float gw = g2-g0+1.f, gh = g3-g1+1.f;
    const float gcx = g0+0.5f*gw, gcy = g1+0.5f*gh;
    float tgt[4];
    tgt[0] = (gcx-ecx)/ew;
    tgt[1] = (gcy-ecy)/eh;
    tgt[2] = logf(gw/ew);
    tgt[3] = logf(gh/eh);
#pragma unroll
    for (int j=0;j<4;j++) {
      const float d = bbox_out[(a*4+j)*HW+hw];
      const float diff = d - tgt[j];
      const float ad = fabsf(diff);
      bx += (ad < (1.0f/9.0f)) ? (4.5f*diff*diff) : (ad - 0.5f/9.0f);
    }
  }
  sce[threadIdx.x]=ce; sbx[threadIdx.x]=bx;
  __syncthreads();
  for (int s=128;s>0;s>>=1) {
    if ((int)threadIdx.x<s) { sce[threadIdx.x]+=sce[threadIdx.x+s]; sbx[threadIdx.x]+=sbx[threadIdx.x+s]; }
    __syncthreads();
  }
  if (threadIdx.x==0) lossP[blockIdx.x] = make_float2(sce[0], sbx[0]);
}

// ---------------- K14: final fixed-order reduction -> losses ----------------
__global__ void loss_final(const float2* __restrict__ lossP, const int* __restrict__ exP,
                           float* __restrict__ out)
{
  __shared__ float a[512];
  __shared__ float c[512];
  __shared__ int   e[512];
  const int t = threadIdx.x;
  float2 v = (t < NBLK) ? lossP[t] : make_float2(0.f,0.f);
  int ev = (t < NBLK) ? exP[t] : 0;
  a[t]=v.x; c[t]=v.y; e[t]=ev;
  __syncthreads();
  for (int s=256;s>0;s>>=1) {
    if (t<s) { a[t]+=a[t+s]; c[t]+=c[t+s]; e[t]+=e[t+s]; }
    __syncthreads();
  }
  if (t==0) {
    const float nex = (float)max(e[0], 1);
    out[OUT_POOL+0] = a[0] / nex;
    out[OUT_POOL+1] = c[0] / nex;
  }
}

// ---------------- launcher ----------------
extern "C" void kernel_launch(void* const* d_in, const int* in_sizes, int n_in,
                              void* d_out, int out_size, void* d_ws, size_t ws_size,
                              hipStream_t stream)
{
  const float* feat    = (const float*)d_in[0];
  const float* gt      = (const float*)d_in[1];
  const float* im_info = (const float*)d_in[2];
  const float* rpn_w   = (const float*)d_in[3];
  const float* rpn_b   = (const float*)d_in[4];
  const float* cls_w   = (const float*)d_in[5];
  const float* cls_b   = (const float*)d_in[6];
  const float* bbox_w  = (const float*)d_in[7];
  const float* bbox_b  = (const float*)d_in[8];
  float* out = (float*)d_out;
  char* ws = (char*)d_ws;

  size_t off = 0;
  auto alloc = [&](size_t bytes) {
    size_t o = off;
    off = (off + bytes + 255) & ~(size_t)255;
    return o;
  };
  // zero-region (memset every call): counter, gtmax keys, thresh, histogram
  size_t o_counter = alloc(4);
  size_t o_gtmax   = alloc(32);
  size_t o_thresh  = alloc(4);
  size_t o_hist    = alloc(65536*4);
  size_t zeroBytes = off;
  // rest of scratch
  size_t o_rpn    = alloc((size_t)CMID*HW*4);
  size_t o_cls    = alloc((size_t)18*HW*4);
  size_t o_bbox   = alloc((size_t)36*HW*4);
  size_t o_keys   = alloc((size_t)NA*8);
  size_t o_props  = alloc((size_t)NA*16);
  size_t o_cand   = alloc((size_t)NA*8);
  size_t o_sprops = alloc((size_t)PRE*16);
  size_t o_mask   = alloc((size_t)PRE*NW*8);
  size_t o_rois   = alloc((size_t)POST*5*4);
  size_t o_tab    = alloc((size_t)POST*49*sizeof(Samp));
  size_t o_ov     = alloc((size_t)NA*8*4);
  size_t o_lab    = alloc((size_t)NA);
  size_t o_amax   = alloc((size_t)NA);
  size_t o_exP    = alloc((size_t)NBLK*4);
  size_t o_lossP  = alloc((size_t)NBLK*8);
  (void)ws_size; (void)in_sizes; (void)n_in; (void)out_size;

  hipMemsetAsync(ws, 0, zeroBytes, stream);

  float* rpn      = (float*)(ws + o_rpn);
  float* cls_out  = (float*)(ws + o_cls);
  float* bbox_out = (float*)(ws + o_bbox);
  u64*   keys     = (u64*)(ws + o_keys);
  float4* props   = (float4*)(ws + o_props);
  u64*   cand     = (u64*)(ws + o_cand);
  float4* sprops  = (float4*)(ws + o_sprops);
  u64*   maskp    = (u64*)(ws + o_mask);
  float* rois     = (float*)(ws + o_rois);
  Samp*  tab      = (Samp*)(ws + o_tab);
  float* ovp      = (float*)(ws + o_ov);
  signed char* labels = (signed char*)(ws + o_lab);
  signed char* amax   = (signed char*)(ws + o_amax);
  int*    exP     = (int*)(ws + o_exP);
  float2* lossP   = (float2*)(ws + o_lossP);
  u32* counter    = (u32*)(ws + o_counter);
  u32* gtmaxp     = (u32*)(ws + o_gtmax);
  u32* thresh     = (u32*)(ws + o_thresh);
  u32* hist       = (u32*)(ws + o_hist);

  // proposal path
  rpn_conv3<<<dim3(8,32), 512, 0, stream>>>(feat, rpn_w, rpn_b, rpn);
  conv1x1<<<144, 64, 0, stream>>>(rpn, cls_w, cls_b, bbox_w, bbox_b, cls_out, bbox_out);
  score_decode<<<NBLK, 256, 0, stream>>>(cls_out, bbox_out, im_info, keys, props, hist);
  hist_scan<<<1, 1024, 0, stream>>>(hist, thresh);
  collect_cand<<<NBLK, 256, 0, stream>>>(keys, thresh, counter, cand);
  rank_scatter<<<NBLK, 256, 0, stream>>>(cand, counter, props, sprops);
  nms_mask<<<dim3(NW, NW), 64, 0, stream>>>(sprops, maskp);
  nms_scan<<<1, 64, 0, stream>>>(maskp, sprops, rois);
  roi_table<<<(POST*49+255)/256, 256, 0, stream>>>(rois, tab);
  roi_pool<<<OUT_POOL/256, 256, 0, stream>>>(feat, tab, out);
  // loss path
  anchor_ov<<<NBLK, 256, 0, stream>>>(gt, im_info, ovp, gtmaxp);
  anchor_label<<<NBLK, 256, 0, stream>>>(ovp, gtmaxp, labels, amax, exP);
  loss_partial<<<NBLK, 256, 0, stream>>>(cls_out, bbox_out, gt, labels, amax, lossP);
  loss_final<<<1, 512, 0, stream>>>(lossP, exP, out);
}

// Round 3
// 1301.873 us; speedup vs baseline: 2.1576x; 2.1576x over previous
//
#include <hip/hip_runtime.h>
#include <stdint.h>

typedef unsigned int u32;
typedef unsigned long long u64;
typedef _Float16 f16x8 __attribute__((ext_vector_type(8)));
typedef float f32x4 __attribute__((ext_vector_type(4)));

#define HF 96
#define HW 9216           // 96*96
#define CIN 1024
#define CMID 512
#define NA 82944          // HW*9
#define PRE 12000
#define POST 300
#define NW 188            // ceil(PRE/64)
#define NBLK 324          // NA/256
#define OUT_POOL (POST*CIN*49)

// base anchors, exact per np.round (banker's) of the reference generator
__device__ __constant__ float BA[9][4] = {
  {-84.f,-40.f,99.f,55.f}, {-176.f,-88.f,191.f,103.f}, {-360.f,-184.f,375.f,199.f},
  {-56.f,-56.f,71.f,71.f}, {-120.f,-120.f,135.f,135.f}, {-248.f,-248.f,263.f,263.f},
  {-36.f,-80.f,51.f,95.f}, {-80.f,-168.f,95.f,183.f},  {-168.f,-344.f,183.f,359.f}
};

__device__ __forceinline__ u32 fkey(float f) {
  u32 u = __float_as_uint(f);
  return (u & 0x80000000u) ? ~u : (u | 0x80000000u);
}

__device__ __forceinline__ void gl_lds16(const void* g, void* l) {
  __builtin_amdgcn_global_load_lds((const __attribute__((address_space(1))) void*)g,
                                   (__attribute__((address_space(3))) void*)l, 16, 0, 0);
}

// ---------------- P1: feat -> swizzled fp16 hi/lo image with halo ----------------
// img[kt(32)][yy(98)][col(98)][8 chunks of 16B]; chunk c: 0-3 hi(ci=kt*32+c*8..+7), 4-7 lo'
// physical chunk = c ^ ((col + 2*y)&7); halo rows/cols zero.
__global__ void prep_img(const float* __restrict__ feat, f16x8* __restrict__ img)
{
  const int t = blockIdx.x*256 + threadIdx.x;   // 32*98*98*8 total
  const int c = t & 7;
  int u = t >> 3;
  const int col = u % 98; u /= 98;
  const int yy = u % 98;
  const int kt = u / 98;
  const int y = yy - 1, x = col - 1;
  f16x8 val;
#pragma unroll
  for (int i=0;i<8;i++) val[i] = (_Float16)0.f;
  if ((unsigned)y < 96u && (unsigned)x < 96u) {
    const int cib = kt*32 + (c&3)*8;
    const float* fp = feat + (size_t)cib*HW + y*96 + x;
#pragma unroll
    for (int i=0;i<8;i++) {
      const float v = fp[(size_t)i*HW];
      if (c < 4) val[i] = (_Float16)v;
      else { const _Float16 hi = (_Float16)v; val[i] = (_Float16)((v - (float)hi)*1024.f); }
    }
  }
  const int sw = (col + 2*y) & 7;
  img[(size_t)((kt*98 + yy)*98 + col)*8 + (c ^ sw)] = val;
}

// ---------------- P2: weights -> frag-ready hi/lo (x64 pre-scale) ----------------
// wbuf[tap(9)][half(2)][ci_chunk(128)][co(512)] of f16x8 (8 ci inner)
__global__ void prep_w(const float* __restrict__ w, f16x8* __restrict__ wbuf)
{
  const int t = blockIdx.x*256 + threadIdx.x;   // 65536 total
  const int co = t & 511;
  const int cic = t >> 9;                        // 0..127
  const float* wp = w + (size_t)co*9216 + cic*72;
#pragma unroll
  for (int tap=0; tap<9; ++tap) {
    f16x8 hv, lv;
#pragma unroll
    for (int i=0;i<8;i++) {
      const float v = wp[i*9 + tap] * 64.f;
      const _Float16 hi = (_Float16)v;
      hv[i] = hi;
      lv[i] = (_Float16)((v - (float)hi)*1024.f);
    }
    wbuf[(size_t)(tap*2+0)*65536 + (size_t)cic*512 + co] = hv;
    wbuf[(size_t)(tap*2+1)*65536 + (size_t)cic*512 + co] = lv;
  }
}

// ---------------- K1: 3x3 conv via split-fp16 MFMA ----------------
// block: 256 thr (4 waves), tile BM=64 co x BN=192 px (2 rows); grid (48, 8)
// per wave: 4 co-tiles x 3 pix-tiles; A-frags from global wbuf, B from LDS.
__global__ __launch_bounds__(256, 2) void rpn_conv_mfma(
    const f16x8* __restrict__ img, const f16x8* __restrict__ wbuf,
    const float* __restrict__ bias, float* __restrict__ out)
{
  __shared__ f16x8 in_s[3136];   // 4 rows x 98 cols x 8 chunks = 50176 B
  const int tid = threadIdx.x;
  const int lane = tid & 63;
  const int wv = tid >> 6;
  const int kgrp = lane >> 4;    // 0..3
  const int co0 = blockIdx.y * 64;
  const int p0 = blockIdx.x * 192;
  const int y0 = blockIdx.x * 2;

  int slot8[3], keyb[3], opix[3];
#pragma unroll
  for (int pt=0; pt<3; ++pt) {
    const int pixel = p0 + wv*48 + pt*16 + (lane & 15);
    const int y = pixel/96, x = pixel - y*96;
    const int col = x + 1;
    const int r = y - y0 + 1;
    slot8[pt] = (r*98 + col)*8;
    keyb[pt] = col + 2*y;
    opix[pt] = pixel;
  }

  f32x4 acc1[4][3], acc2[4][3];
#pragma unroll
  for (int c=0;c<4;c++)
#pragma unroll
    for (int pt=0;pt<3;pt++) {
      acc1[c][pt] = (f32x4){0.f,0.f,0.f,0.f};
      acc2[c][pt] = (f32x4){0.f,0.f,0.f,0.f};
    }

  const size_t wbl = (size_t)(kgrp*512 + co0 + (lane & 15));

  for (int kt = 0; kt < 32; ++kt) {
    __syncthreads();
    {
      const f16x8* gsrc = img + (size_t)(kt*98 + y0)*98*8;
      for (int j = wv; j < 49; j += 4)
        gl_lds16(gsrc + j*64 + lane, in_s + j*64);
    }
    asm volatile("s_waitcnt vmcnt(0)" ::: "memory");
    __syncthreads();

    const size_t wk = (size_t)kt*2048 + wbl;
#pragma unroll
    for (int t=0; t<9; ++t) {
      const int dy = t/3 - 1, dx = t%3 - 1;
      const int so8 = (dy*98 + dx)*8;
      f16x8 af[4][2];
#pragma unroll
      for (int c=0;c<4;c++)
#pragma unroll
        for (int h=0;h<2;h++)
          af[c][h] = wbuf[(size_t)t*131072 + (size_t)h*65536 + wk + c*16];
      f16x8 bf[3][2];
#pragma unroll
      for (int pt=0;pt<3;pt++) {
        const int key = (keyb[pt] + dx + 2*dy) & 7;
        const int base = slot8[pt] + so8;
#pragma unroll
        for (int h=0;h<2;h++)
          bf[pt][h] = in_s[base + ((h*4 + kgrp) ^ key)];
      }
#pragma unroll
      for (int c=0;c<4;c++)
#pragma unroll
        for (int pt=0;pt<3;pt++) {
          acc1[c][pt] = __builtin_amdgcn_mfma_f32_16x16x32_f16(af[c][0], bf[pt][0], acc1[c][pt], 0,0,0);
          acc2[c][pt] = __builtin_amdgcn_mfma_f32_16x16x32_f16(af[c][0], bf[pt][1], acc2[c][pt], 0,0,0);
          acc2[c][pt] = __builtin_amdgcn_mfma_f32_16x16x32_f16(af[c][1], bf[pt][0], acc2[c][pt], 0,0,0);
        }
    }
  }

#pragma unroll
  for (int c=0;c<4;c++) {
#pragma unroll
    for (int i=0;i<4;i++) {
      const int co = co0 + c*16 + kgrp*4 + i;
      const float bb = bias[co];
#pragma unroll
      for (int pt=0;pt<3;pt++) {
        const float v = (acc1[c][pt][i] + acc2[c][pt][i]*(1.f/1024.f))*(1.f/64.f) + bb;
        out[(size_t)co*HW + opix[pt]] = v > 0.f ? v : 0.f;
      }
    }
  }
}

// ---------------- K2: 1x1 convs (cls 18 + bbox 36) ----------------
__global__ void conv1x1(const float* __restrict__ rpn,
    const float* __restrict__ cw, const float* __restrict__ cb,
    const float* __restrict__ bw, const float* __restrict__ bb,
    float* __restrict__ cls_out, float* __restrict__ bbox_out)
{
  const int hw = blockIdx.x * 64 + threadIdx.x;
  float accA[18], accB[36];
#pragma unroll
  for (int c=0;c<18;c++) accA[c]=0.f;
#pragma unroll
  for (int c=0;c<36;c++) accB[c]=0.f;
  for (int ci=0; ci<CMID; ++ci) {
    const float v = rpn[ci*HW + hw];
#pragma unroll
    for (int c=0;c<18;c++) accA[c] = fmaf(v, cw[c*CMID+ci], accA[c]);
#pragma unroll
    for (int c=0;c<36;c++) accB[c] = fmaf(v, bw[c*CMID+ci], accB[c]);
  }
#pragma unroll
  for (int c=0;c<18;c++) cls_out[c*HW+hw] = accA[c] + cb[c];
#pragma unroll
  for (int c=0;c<36;c++) bbox_out[c*HW+hw] = accB[c] + bb[c];
}

// ---------------- K3: scores (softmax fg), keys, histogram, decode+clip ----------------
__global__ void score_decode(const float* __restrict__ cls_out,
    const float* __restrict__ bbox_out, const float* __restrict__ im_info,
    u64* __restrict__ keys, float4* __restrict__ props, u32* __restrict__ hist)
{
#pragma clang fp contract(off)
  const int n = blockIdx.x*256 + threadIdx.x;
  const int hw = n / 9;
  const int a  = n - hw*9;
  const int x = hw % HF, y = hw / HF;
  const float l0 = cls_out[a*HW + hw];
  const float l1 = cls_out[(9+a)*HW + hw];
  const float m = fmaxf(l0, l1);
  const float e0 = expf(l0 - m), e1 = expf(l1 - m);
  const float s = e1 / (e0 + e1);
  const u32 sb = __float_as_uint(s);      // s >= 0 -> bits monotone
  keys[n] = ((u64)(~sb) << 32) | (u32)n;  // asc key == desc score, tie -> asc idx
  atomicAdd(&hist[sb >> 16], 1u);

  const float ax1 = BA[a][0] + 16.f*(float)x;
  const float ay1 = BA[a][1] + 16.f*(float)y;
  const float ax2 = BA[a][2] + 16.f*(float)x;
  const float ay2 = BA[a][3] + 16.f*(float)y;
  const float aw = ax2 - ax1 + 1.f, ah = ay2 - ay1 + 1.f;
  const float cx = ax1 + 0.5f*aw,  cy = ay1 + 0.5f*ah;
  const float d0 = bbox_out[(a*4+0)*HW + hw];
  const float d1 = bbox_out[(a*4+1)*HW + hw];
  const float d2 = bbox_out[(a*4+2)*HW + hw];
  const float d3 = bbox_out[(a*4+3)*HW + hw];
  const float pcx = d0*aw + cx, pcy = d1*ah + cy;
  const float pw = expf(d2)*aw, ph = expf(d3)*ah;
  const float imh = im_info[0], imw = im_info[1];
  float bx1 = fminf(fmaxf(pcx - 0.5f*pw, 0.f), imw - 1.f);
  float by1 = fminf(fmaxf(pcy - 0.5f*ph, 0.f), imh - 1.f);
  float bx2 = fminf(fmaxf(pcx + 0.5f*pw, 0.f), imw - 1.f);
  float by2 = fminf(fmaxf(pcy + 0.5f*ph, 0.f), imh - 1.f);
  props[n] = make_float4(bx1, by1, bx2, by2);
}

// ---------------- K4: find threshold bucket ----------------
__global__ void hist_scan(const u32* __restrict__ hist, u32* __restrict__ thresh)
{
  __shared__ u32 csum[1024];
  const int t = threadIdx.x;
  u32 s = 0;
  for (int i=0;i<64;i++) s += hist[t*64+i];
  csum[t] = s;
  __syncthreads();
  if (t == 0) {
    u32 cum = 0;
    int tc = 1023;
    for (; tc >= 0; --tc) {
      if (cum + csum[tc] >= PRE) break;
      cum += csum[tc];
    }
    u32 b = (u32)tc*64u + 63u;
    for (;;) { cum += hist[b]; if (cum >= PRE) break; --b; }
    thresh[0] = b;
  }
}

// ---------------- K5: compact candidates ----------------
__global__ void collect_cand(const u64* __restrict__ keys, const u32* __restrict__ thresh,
                             u32* __restrict__ counter, u64* __restrict__ cand)
{
  const int n = blockIdx.x*256 + threadIdx.x;
  const u64 k = keys[n];
  const u32 sb = ~(u32)(k >> 32);
  if ((sb >> 16) >= thresh[0]) {
    u32 p = atomicAdd(counter, 1u);
    cand[p] = k;
  }
}

// ---------------- K6: exact rank among candidates -> scatter sorted boxes ----------------
__global__ void rank_scatter(const u64* __restrict__ cand, const u32* __restrict__ counter,
                             const float4* __restrict__ props, float4* __restrict__ sprops)
{
  __shared__ u64 sk[256];
  const int M = (int)counter[0];
  if (blockIdx.x*256 >= M) return;        // block-uniform
  const int i = blockIdx.x*256 + threadIdx.x;
  const u64 key = (i < M) ? cand[i] : ~0ull;
  int rank = 0;
  for (int t0 = 0; t0 < M; t0 += 256) {
    const int j = t0 + threadIdx.x;
    sk[threadIdx.x] = (j < M) ? cand[j] : ~0ull;
    __syncthreads();
#pragma unroll 8
    for (int k=0;k<256;k++) rank += (sk[k] < key) ? 1 : 0;
    __syncthreads();
  }
  if (i < M && rank < PRE) sprops[rank] = props[(u32)key];
}

// ---------------- K7: NMS suppression bitmask ----------------
__global__ void nms_mask(const float4* __restrict__ sp, u64* __restrict__ mask)
{
#pragma clang fp contract(off)
  __shared__ float4 cb[64];
  __shared__ float  ca[64];
  const int c0 = blockIdx.x * 64;
  const int cend = min(64, PRE - c0);
  if ((int)threadIdx.x < cend) {
    float4 b = sp[c0 + threadIdx.x];
    cb[threadIdx.x] = b;
    ca[threadIdx.x] = (b.z-b.x+1.f)*(b.w-b.y+1.f);
  }
  __syncthreads();
  const int row = blockIdx.y*64 + threadIdx.x;
  if (row >= PRE) return;
  const float4 rb = sp[row];
  const float ra = (rb.z-rb.x+1.f)*(rb.w-rb.y+1.f);
  u64 bits = 0;
  for (int j=0;j<cend;j++) {
    const float4 c = cb[j];
    const float xx1 = fmaxf(rb.x, c.x), yy1 = fmaxf(rb.y, c.y);
    const float xx2 = fminf(rb.z, c.z), yy2 = fminf(rb.w, c.w);
    const float inter = fmaxf(xx2-xx1+1.f, 0.f) * fmaxf(yy2-yy1+1.f, 0.f);
    const float iou = inter / (ra + ca[j] - inter);
    if (iou > 0.7f) bits |= (1ull << j);
  }
  mask[(size_t)row*NW + blockIdx.x] = bits;
}

// ---------------- K8: serial greedy scan (one wave) -> rois ----------------
__global__ void nms_scan(const u64* __restrict__ mask, const float4* __restrict__ sp,
                         float* __restrict__ rois)
{
  __shared__ int keep_s[POST];
  const int l = threadIdx.x;               // lane l owns words 3l..3l+2
  u64 v[3];
#pragma unroll
  for (int q=0;q<3;q++) {
    const int w = l*3+q;
    u64 val = 0;
    if (w < NW) { val = ~0ull; if (w == NW-1) val = (1ull<<32) - 1ull; }
    v[q] = val;
  }
  for (int it=0; it<POST; ++it) {
    const u64 nz = v[0] | v[1] | v[2];
    const u64 bal = __ballot(nz != 0);
    int idx;
    if (bal == 0) idx = -1;
    else {
      const int src = __ffsll((unsigned long long)bal) - 1;
      int fi = 0;
      if (v[0])      fi = (l*3+0)*64 + __ffsll(v[0]) - 1;
      else if (v[1]) fi = (l*3+1)*64 + __ffsll(v[1]) - 1;
      else if (v[2]) fi = (l*3+2)*64 + __ffsll(v[2]) - 1;
      idx = __shfl(fi, src);
    }
    if (l == 0) keep_s[it] = (idx < 0) ? 0 : idx;
    if (idx >= 0) {
      const u64* mrow = mask + (size_t)idx*NW;
#pragma unroll
      for (int q=0;q<3;q++) {
        const int w = l*3+q;
        if (w < NW) v[q] &= ~mrow[w];
      }
    }
  }
  __syncthreads();
  for (int i = l; i < POST; i += 64) {
    const float4 b = sp[keep_s[i]];
    rois[i*5+0] = 0.f;
    rois[i*5+1] = b.x; rois[i*5+2] = b.y; rois[i*5+3] = b.z; rois[i*5+4] = b.w;
  }
}

// ---------------- K9/K10: ROI bilinear crop ----------------
struct __align__(16) Samp { int p0,p1,p2,p3; float w0,w1,w2,w3; };

__global__ void roi_table(const float* __restrict__ rois, Samp* __restrict__ tab)
{
#pragma clang fp contract(off)
  const int idx = blockIdx.x*256 + threadIdx.x;
  if (idx >= POST*49) return;
  const int r = idx / 49;
  const int s = idx - r*49;
  const int py = s / 7, px = s - py*7;
  const float x1 = rois[r*5+1] * 0.0625f;
  const float y1 = rois[r*5+2] * 0.0625f;
  const float x2 = rois[r*5+3] * 0.0625f;
  const float y2 = rois[r*5+4] * 0.0625f;
  const float t00 = (x2-x1)/95.f;
  const float t02 = (x1+x2-95.f)/95.f;
  const float t11 = (y2-y1)/95.f;
  const float t12 = (y1+y2-95.f)/95.f;
  const float lx = (float)(px-3)/3.f;
  const float ly = (float)(py-3)/3.f;
  const float gx = t00*lx + t02;
  const float gy = t11*ly + t12;
  const float ix = (gx+1.f)*0.5f*95.f;
  const float iy = (gy+1.f)*0.5f*95.f;
  const float ix0 = floorf(ix), iy0 = floorf(iy);
  const float wx = ix-ix0, wy = iy-iy0;
  const float xs[2] = {ix0, ix0+1.f};
  const float ys[2] = {iy0, iy0+1.f};
  const float wxs[2] = {1.f-wx, wx};
  const float wys[2] = {1.f-wy, wy};
  int pos[4]; float wt[4];
#pragma unroll
  for (int k=0;k<4;k++) {
    const int dy = k>>1, dx = k&1;
    const float yi = ys[dy], xi = xs[dx];
    const bool valid = (yi>=0.f)&&(yi<96.f)&&(xi>=0.f)&&(xi<96.f);
    const int yc = (int)fminf(fmaxf(yi,0.f),95.f);
    const int xc = (int)fminf(fmaxf(xi,0.f),95.f);
    pos[k] = yc*96+xc;
    wt[k] = wys[dy]*wxs[dx] * (valid?1.f:0.f);
  }
  Samp t;
  t.p0=pos[0]; t.p1=pos[1]; t.p2=pos[2]; t.p3=pos[3];
  t.w0=wt[0];  t.w1=wt[1];  t.w2=wt[2];  t.w3=wt[3];
  tab[idx] = t;
}

__global__ void roi_pool(const float* __restrict__ feat, const Samp* __restrict__ tab,
                         float* __restrict__ out)
{
#pragma clang fp contract(off)
  const int o = blockIdx.x*256 + threadIdx.x;   // grid exact: OUT_POOL/256
  const int s  = o % 49;
  const int rc = o / 49;
  const int c = rc & (CIN-1);
  const int r = rc >> 10;
  const Samp t = tab[r*49+s];
  const float* f = feat + (size_t)c*HW;
  out[o] = t.w0*f[t.p0] + t.w1*f[t.p1] + t.w2*f[t.p2] + t.w3*f[t.p3];
}

// ---------------- K11: anchor-gt IoU matrix (masked) + per-gt max ----------------
__global__ void anchor_ov(const float* __restrict__ gt, const float* __restrict__ im_info,
                          float* __restrict__ ov, u32* __restrict__ gtmax)
{
#pragma clang fp contract(off)
  __shared__ u32 lmax[8];
  if (threadIdx.x < 8) lmax[threadIdx.x] = 0u;
  __syncthreads();
  const int n = blockIdx.x*256 + threadIdx.x;
  const int hw = n/9, a = n - hw*9;
  const int x = hw % HF, y = hw / HF;
  const float ax1 = BA[a][0]+16.f*(float)x, ay1 = BA[a][1]+16.f*(float)y;
  const float ax2 = BA[a][2]+16.f*(float)x, ay2 = BA[a][3]+16.f*(float)y;
  const float imh = im_info[0], imw = im_info[1];
  const bool inside = (ax1 >= 0.f) && (ay1 >= 0.f) && (ax2 < imw) && (ay2 < imh);
  const float aa = (ax2-ax1+1.f)*(ay2-ay1+1.f);
#pragma unroll
  for (int j=0;j<8;j++) {
    const float g0=gt[j*5+0], g1=gt[j*5+1], g2=gt[j*5+2], g3=gt[j*5+3];
    const float ga = (g2-g0+1.f)*(g3-g1+1.f);
    const float xx1 = fmaxf(ax1,g0), yy1 = fmaxf(ay1,g1);
    const float xx2 = fminf(ax2,g2), yy2 = fminf(ay2,g3);
    const float inter = fmaxf(xx2-xx1+1.f,0.f)*fmaxf(yy2-yy1+1.f,0.f);
    const float iou = inter/(aa+ga-inter);
    const float o = inside ? iou : -1.f;
    ov[(size_t)n*8+j] = o;
    atomicMax(&lmax[j], fkey(o));
  }
  __syncthreads();
  if (threadIdx.x < 8) atomicMax(&gtmax[threadIdx.x], lmax[threadIdx.x]);
}

// ---------------- K12: labels + argmax + ex-count partials ----------------
__global__ void anchor_label(const float* __restrict__ ov, const u32* __restrict__ gtmax,
                             signed char* __restrict__ labels, signed char* __restrict__ amax,
                             int* __restrict__ exP)
{
  __shared__ int se[256];
  const int n = blockIdx.x*256 + threadIdx.x;
  float best = -3.402823466e38f;
  int arg = 0;
  bool isbest = false;
#pragma unroll
  for (int j=0;j<8;j++) {
    const float o = ov[(size_t)n*8+j];
    if (o > best) { best = o; arg = j; }
    if (fkey(o) == gtmax[j]) isbest = true;
  }
  const bool inside = ov[(size_t)n*8+0] >= 0.f;
  int lab = -1;
  if (inside && best < 0.3f) lab = 0;
  if (inside && isbest) lab = 1;
  if (inside && best >= 0.7f) lab = 1;
  labels[n] = (signed char)lab;
  amax[n] = (signed char)arg;
  se[threadIdx.x] = (lab >= 0) ? 1 : 0;
  __syncthreads();
  for (int s=128; s>0; s>>=1) {
    if ((int)threadIdx.x < s) se[threadIdx.x] += se[threadIdx.x+s];
    __syncthreads();
  }
  if (threadIdx.x==0) exP[blockIdx.x] = se[0];
}

// ---------------- K13: per-anchor loss terms -> block partials ----------------
__global__ void loss_partial(const float* __restrict__ cls_out, const float* __restrict__ bbox_out,
                             const float* __restrict__ gt, const signed char* __restrict__ labels,
                             const signed char* __restrict__ amax, float2* __restrict__ lossP)
{
#pragma clang fp contract(off)
  __shared__ float sce[256];
  __shared__ float sbx[256];
  const int n = blockIdx.x*256 + threadIdx.x;
  const int hw = n/9, a = n - hw*9;
  const int lab = labels[n];
  float ce = 0.f, bx = 0.f;
  if (lab >= 0) {
    const float l0 = cls_out[a*HW+hw], l1 = cls_out[(9+a)*HW+hw];
    const float m = fmaxf(l0,l1);
    const float lse = m + logf(expf(l0-m)+expf(l1-m));
    ce = lse - (lab==1 ? l1 : l0);
  }
  if (lab == 1) {
    const int x = hw % HF, y = hw / HF;
    const float ax1 = BA[a][0]+16.f*(float)x, ay1 = BA[a][1]+16.f*(float)y;
    const float ax2 = BA[a][2]+16.f*(float)x, ay2 = BA[a][3]+16.f*(float)y;
    const float ew = ax2-ax1+1.f, eh = ay2-ay1+1.f;
    const float ecx = ax1+0.5f*ew, ecy = ay1+0.5f*eh;
    const int g = amax[n];
    const float g0=gt[g*5+0], g1=gt[g*5+1], g2=gt[g*5+2], g3=gt[g*5+3];
    const float gw = g2-g0+1.f, gh = g3-g1+1.f;
    const float gcx = g0+0.5f*gw, gcy = g1+0.5f*gh;
    float tgt[4];
    tgt[0] = (gcx-ecx)/ew;
    tgt[1] = (gcy-ecy)/eh;
    tgt[2] = logf(gw/ew);
    tgt[3] = logf(gh/eh);
#pragma unroll
    for (int j=0;j<4;j++) {
      const float d = bbox_out[(a*4+j)*HW+hw];
      const float diff = d - tgt[j];
      const float ad = fabsf(diff);
      bx += (ad < (1.0f/9.0f)) ? (4.5f*diff*diff) : (ad - 0.5f/9.0f);
    }
  }
  sce[threadIdx.x]=ce; sbx[threadIdx.x]=bx;
  __syncthreads();
  for (int s=128;s>0;s>>=1) {
    if ((int)threadIdx.x<s) { sce[threadIdx.x]+=sce[threadIdx.x+s]; sbx[threadIdx.x]+=sbx[threadIdx.x+s]; }
    __syncthreads();
  }
  if (threadIdx.x==0) lossP[blockIdx.x] = make_float2(sce[0], sbx[0]);
}

// ---------------- K14: final fixed-order reduction -> losses ----------------
__global__ void loss_final(const float2* __restrict__ lossP, const int* __restrict__ exP,
                           float* __restrict__ out)
{
  __shared__ float a[512];
  __shared__ float c[512];
  __shared__ int   e[512];
  const int t = threadIdx.x;
  float2 v = (t < NBLK) ? lossP[t] : make_float2(0.f,0.f);
  int ev = (t < NBLK) ? exP[t] : 0;
  a[t]=v.x; c[t]=v.y; e[t]=ev;
  __syncthreads();
  for (int s=256;s>0;s>>=1) {
    if (t<s) { a[t]+=a[t+s]; c[t]+=c[t+s]; e[t]+=e[t+s]; }
    __syncthreads();
  }
  if (t==0) {
    const float nex = (float)max(e[0], 1);
    out[OUT_POOL+0] = a[0] / nex;
    out[OUT_POOL+1] = c[0] / nex;
  }
}

// ---------------- launcher ----------------
extern "C" void kernel_launch(void* const* d_in, const int* in_sizes, int n_in,
                              void* d_out, int out_size, void* d_ws, size_t ws_size,
                              hipStream_t stream)
{
  const float* feat    = (const float*)d_in[0];
  const float* gt      = (const float*)d_in[1];
  const float* im_info = (const float*)d_in[2];
  const float* rpn_w   = (const float*)d_in[3];
  const float* rpn_b   = (const float*)d_in[4];
  const float* cls_w   = (const float*)d_in[5];
  const float* cls_b   = (const float*)d_in[6];
  const float* bbox_w  = (const float*)d_in[7];
  const float* bbox_b  = (const float*)d_in[8];
  float* out = (float*)d_out;
  char* ws = (char*)d_ws;

  size_t off = 0;
  auto alloc = [&](size_t bytes) {
    size_t o = off;
    off = (off + bytes + 255) & ~(size_t)255;
    return o;
  };
  // zero-region (memset every call)
  size_t o_counter = alloc(4);
  size_t o_gtmax   = alloc(32);
  size_t o_thresh  = alloc(4);
  size_t o_hist    = alloc(65536*4);
  size_t zeroBytes = off;
  // persistent across both phases
  size_t o_cls  = alloc((size_t)18*HW*4);
  size_t o_bbox = alloc((size_t)36*HW*4);
  size_t o_rpn  = alloc((size_t)CMID*HW*4);
  // overlapped region R: phase A (img,wbuf for conv) then phase C (proposal/loss scratch)
  size_t o_R = off;
  size_t o_img  = o_R;                    // 39,337,984 B
  size_t o_wbuf = o_R + 39337984;         // 18,874,368 B
  // phase C sub-allocations inside R (first writes all occur after conv completes)
  size_t coff = o_R;
  auto calloc2 = [&](size_t bytes) {
    size_t o = coff;
    coff = (coff + bytes + 255) & ~(size_t)255;
    return o;
  };
  size_t o_keys   = calloc2((size_t)NA*8);
  size_t o_props  = calloc2((size_t)NA*16);
  size_t o_cand   = calloc2((size_t)NA*8);
  size_t o_sprops = calloc2((size_t)PRE*16);
  size_t o_mask   = calloc2((size_t)PRE*NW*8);
  size_t o_rois   = calloc2((size_t)POST*5*4);
  size_t o_tab    = calloc2((size_t)POST*49*sizeof(Samp));
  size_t o_ov     = calloc2((size_t)NA*8*4);
  size_t o_lab    = calloc2((size_t)NA);
  size_t o_amax   = calloc2((size_t)NA);
  size_t o_exP    = calloc2((size_t)NBLK*4);
  size_t o_lossP  = calloc2((size_t)NBLK*8);
  (void)ws_size; (void)in_sizes; (void)n_in; (void)out_size;

  hipMemsetAsync(ws, 0, zeroBytes, stream);

  f16x8* img      = (f16x8*)(ws + o_img);
  f16x8* wbuf     = (f16x8*)(ws + o_wbuf);
  float* rpn      = (float*)(ws + o_rpn);
  float* cls_out  = (float*)(ws + o_cls);
  float* bbox_out = (float*)(ws + o_bbox);
  u64*   keys     = (u64*)(ws + o_keys);
  float4* props   = (float4*)(ws + o_props);
  u64*   cand     = (u64*)(ws + o_cand);
  float4* sprops  = (float4*)(ws + o_sprops);
  u64*   maskp    = (u64*)(ws + o_mask);
  float* rois     = (float*)(ws + o_rois);
  Samp*  tab      = (Samp*)(ws + o_tab);
  float* ovp      = (float*)(ws + o_ov);
  signed char* labels = (signed char*)(ws + o_lab);
  signed char* amax   = (signed char*)(ws + o_amax);
  int*    exP     = (int*)(ws + o_exP);
  float2* lossP   = (float2*)(ws + o_lossP);
  u32* counter    = (u32*)(ws + o_counter);
  u32* gtmaxp     = (u32*)(ws + o_gtmax);
  u32* thresh     = (u32*)(ws + o_thresh);
  u32* hist       = (u32*)(ws + o_hist);

  // phase A: conv via split-fp16 MFMA
  prep_img<<<9604, 256, 0, stream>>>(feat, img);
  prep_w<<<256, 256, 0, stream>>>(rpn_w, wbuf);
  rpn_conv_mfma<<<dim3(48, 8), 256, 0, stream>>>(img, wbuf, rpn_b, rpn);
  conv1x1<<<144, 64, 0, stream>>>(rpn, cls_w, cls_b, bbox_w, bbox_b, cls_out, bbox_out);
  // phase C: proposals (reuses region R — stream-ordered after conv)
  score_decode<<<NBLK, 256, 0, stream>>>(cls_out, bbox_out, im_info, keys, props, hist);
  hist_scan<<<1, 1024, 0, stream>>>(hist, thresh);
  collect_cand<<<NBLK, 256, 0, stream>>>(keys, thresh, counter, cand);
  rank_scatter<<<NBLK, 256, 0, stream>>>(cand, counter, props, sprops);
  nms_mask<<<dim3(NW, NW), 64, 0, stream>>>(sprops, maskp);
  nms_scan<<<1, 64, 0, stream>>>(maskp, sprops, rois);
  roi_table<<<(POST*49+255)/256, 256, 0, stream>>>(rois, tab);
  roi_pool<<<OUT_POOL/256, 256, 0, stream>>>(feat, tab, out);
  // loss path
  anchor_ov<<<NBLK, 256, 0, stream>>>(gt, im_info, ovp, gtmaxp);
  anchor_label<<<NBLK, 256, 0, stream>>>(ovp, gtmaxp, labels, amax, exP);
  loss_partial<<<NBLK, 256, 0, stream>>>(cls_out, bbox_out, gt, labels, amax, lossP);
  loss_final<<<1, 512, 0, stream>>>(lossP, exP, out);
}

// Round 4
// 1130.267 us; speedup vs baseline: 2.4852x; 1.1518x over previous
//
#include <hip/hip_runtime.h>
#include <stdint.h>

typedef unsigned int u32;
typedef unsigned long long u64;
typedef _Float16 f16x8 __attribute__((ext_vector_type(8)));
typedef float f32x4 __attribute__((ext_vector_type(4)));

#define HF 96
#define HW 9216           // 96*96
#define CIN 1024
#define CMID 512
#define NA 82944          // HW*9
#define PRE 12000
#define POST 300
#define NW 188            // ceil(PRE/64)
#define NBLK 324          // NA/256
#define OUT_POOL (POST*CIN*49)

// base anchors, exact per np.round (banker's) of the reference generator
__device__ __constant__ float BA[9][4] = {
  {-84.f,-40.f,99.f,55.f}, {-176.f,-88.f,191.f,103.f}, {-360.f,-184.f,375.f,199.f},
  {-56.f,-56.f,71.f,71.f}, {-120.f,-120.f,135.f,135.f}, {-248.f,-248.f,263.f,263.f},
  {-36.f,-80.f,51.f,95.f}, {-80.f,-168.f,95.f,183.f},  {-168.f,-344.f,183.f,359.f}
};

__device__ __forceinline__ u32 fkey(float f) {
  u32 u = __float_as_uint(f);
  return (u & 0x80000000u) ? ~u : (u | 0x80000000u);
}

__device__ __forceinline__ void gl_lds16(const void* g, void* l) {
  __builtin_amdgcn_global_load_lds((const __attribute__((address_space(1))) void*)g,
                                   (__attribute__((address_space(3))) void*)l, 16, 0, 0);
}

// ---------------- P1: feat -> swizzled fp16 hi/lo image with halo (coalesced) ----------------
// img[kt(32)][yy(98)][col(98)][8 chunks of 16B]; chunk c: 0-3 hi(ci=kt*32+c*8..+7), 4-7 lo'
// physical chunk = c ^ ((col + 2*y)&7); halo rows/cols zero. grid (98 yy, 32 kt) x 256.
__global__ void prep_img(const float* __restrict__ feat, f16x8* __restrict__ img)
{
  __shared__ float ls[32][100];
  const int yy = blockIdx.x;
  const int kt = blockIdx.y;
  const int tid = threadIdx.x;
  const int y = yy - 1;
  const bool yok = (unsigned)y < 96u;
  if (yok) {
    for (int e = tid; e < 3072; e += 256) {
      const int ci = e / 96;
      const int x = e - ci * 96;
      ls[ci][x] = feat[(size_t)(kt*32 + ci)*HW + y*96 + x];
    }
  }
  __syncthreads();
  for (int idx = tid; idx < 784; idx += 256) {
    const int col = idx >> 3;
    const int q = idx & 7;
    const int x = col - 1;
    f16x8 val;
#pragma unroll
    for (int i=0;i<8;i++) val[i] = (_Float16)0.f;
    if (yok && (unsigned)x < 96u) {
#pragma unroll
      for (int i=0;i<8;i++) {
        const float v = ls[(q&3)*8 + i][x];
        if (q < 4) val[i] = (_Float16)v;
        else { const _Float16 hi = (_Float16)v; val[i] = (_Float16)((v - (float)hi)*1024.f); }
      }
    }
    const int sw = (col + 2*y) & 7;
    img[(size_t)((kt*98 + yy)*98 + col)*8 + (q ^ sw)] = val;
  }
}

// ---------------- P2: weights -> frag-ready hi/lo (x64 pre-scale), kt-major ----------------
// wbuf[kt(32)][tap(9)][half(2)][kgrp(4)][co(512)] of f16x8 (8 ci inner)
__global__ void prep_w(const float* __restrict__ w, f16x8* __restrict__ wbuf)
{
  const int t = blockIdx.x*256 + threadIdx.x;   // 65536 total
  const int co = t & 511;
  const int cic = t >> 9;                        // 0..127
  const int kt = cic >> 2;
  const int kg = cic & 3;
  const float* wp = w + (size_t)co*9216 + cic*72;
#pragma unroll
  for (int tap=0; tap<9; ++tap) {
    f16x8 hv, lv;
#pragma unroll
    for (int i=0;i<8;i++) {
      const float v = wp[i*9 + tap] * 64.f;
      const _Float16 hi = (_Float16)v;
      hv[i] = hi;
      lv[i] = (_Float16)((v - (float)hi)*1024.f);
    }
    wbuf[(size_t)(((kt*9 + tap)*2 + 0)*4 + kg)*512 + co] = hv;
    wbuf[(size_t)(((kt*9 + tap)*2 + 1)*4 + kg)*512 + co] = lv;
  }
}

// ---------------- K1: 3x3 conv via split-fp16 MFMA, single-wave blocks ----------------
// block: 64 thr (1 wave), tile 64 co x 48 px (one y-row); grid (2 xh, 96 y, 8 co)=1536.
// per kt: stage 3 rows x 50 cols (19 KB) via global_load_lds, no barriers needed.
__global__ __launch_bounds__(64) void rpn_conv_mfma(
    const f16x8* __restrict__ img, const f16x8* __restrict__ wbuf,
    const float* __restrict__ bias, float* __restrict__ out)
{
  __shared__ f16x8 in_s[1216];   // 3 rows x 50 cols x 8 chunks = 1200 (+16 pad)
  const int lane = threadIdx.x;
  const int kgrp = lane >> 4;
  const int ln15 = lane & 15;
  const int x0 = blockIdx.x * 48;
  const int y  = blockIdx.y;
  const int co0 = blockIdx.z * 64;

  // precompute per-lane staging source offsets (within a kt slice)
  int goff[19];
#pragma unroll
  for (int j=0;j<19;j++) {
    int s = j*64 + lane; if (s > 1199) s = 1199;
    const int row = s / 400;
    const int rem = s - row*400;
    const int colc = rem >> 3;
    const int ch = rem & 7;
    goff[j] = ((y + row)*98 + x0 + colc)*8 + ch;
  }

  // per-pixel-tile constants
  int keyb[3];
#pragma unroll
  for (int pt=0; pt<3; ++pt) keyb[pt] = x0 + pt*16 + ln15 + 1 + 2*y;

  f32x4 acc1[4][3], acc2[4][3];
#pragma unroll
  for (int c=0;c<4;c++)
#pragma unroll
    for (int pt=0;pt<3;pt++) {
      acc1[c][pt] = (f32x4){0.f,0.f,0.f,0.f};
      acc2[c][pt] = (f32x4){0.f,0.f,0.f,0.f};
    }

  const int wlane = kgrp*512 + co0 + ln15;

  for (int kt = 0; kt < 32; ++kt) {
    // all ds_reads of previous iter must be complete before overwriting LDS
    asm volatile("s_waitcnt lgkmcnt(0)" ::: "memory");
    const f16x8* kbase = img + (size_t)kt*76832;
#pragma unroll
    for (int j=0;j<19;j++) gl_lds16(kbase + goff[j], in_s + j*64);
    asm volatile("s_waitcnt vmcnt(0)" ::: "memory");

#pragma unroll
    for (int t=0; t<9; ++t) {
      const int dy = t/3 - 1, dx = t%3 - 1;
      f16x8 af[4][2];
#pragma unroll
      for (int h=0;h<2;h++) {
        const size_t wb = (size_t)(((kt*9 + t)*2 + h)*2048) + wlane;
#pragma unroll
        for (int c=0;c<4;c++) af[c][h] = wbuf[wb + c*16];
      }
      f16x8 bf[3][2];
#pragma unroll
      for (int pt=0;pt<3;pt++) {
        const int colL = pt*16 + ln15 + dx + 1;      // local padded col
        const int rowL = dy + 1;
        const int key = (keyb[pt] + dx + 2*dy) & 7;
        const int base = (rowL*50 + colL)*8;
#pragma unroll
        for (int h=0;h<2;h++)
          bf[pt][h] = in_s[base + ((h*4 + kgrp) ^ key)];
      }
#pragma unroll
      for (int c=0;c<4;c++)
#pragma unroll
        for (int pt=0;pt<3;pt++) {
          acc1[c][pt] = __builtin_amdgcn_mfma_f32_16x16x32_f16(af[c][0], bf[pt][0], acc1[c][pt], 0,0,0);
          acc2[c][pt] = __builtin_amdgcn_mfma_f32_16x16x32_f16(af[c][0], bf[pt][1], acc2[c][pt], 0,0,0);
          acc2[c][pt] = __builtin_amdgcn_mfma_f32_16x16x32_f16(af[c][1], bf[pt][0], acc2[c][pt], 0,0,0);
        }
    }
  }

  const int pixb = y*96 + x0;
#pragma unroll
  for (int c=0;c<4;c++) {
#pragma unroll
    for (int i=0;i<4;i++) {
      const int co = co0 + c*16 + kgrp*4 + i;
      const float bb = bias[co];
#pragma unroll
      for (int pt=0;pt<3;pt++) {
        const float v = (acc1[c][pt][i] + acc2[c][pt][i]*(1.f/1024.f))*(1.f/64.f) + bb;
        out[(size_t)co*HW + pixb + pt*16 + ln15] = v > 0.f ? v : 0.f;
      }
    }
  }
}

// ---------------- K2: 1x1 convs — ci-split partials + deterministic reduce ----------------
__global__ void conv1x1p(const float* __restrict__ rpn,
    const float* __restrict__ cw, const float* __restrict__ bw,
    float* __restrict__ partial)
{
  const int hw = blockIdx.x * 64 + threadIdx.x;
  const int cg = blockIdx.y;           // 0..3
  const int ci0 = cg * 128;
  float accA[18], accB[36];
#pragma unroll
  for (int c=0;c<18;c++) accA[c]=0.f;
#pragma unroll
  for (int c=0;c<36;c++) accB[c]=0.f;
  for (int ci=ci0; ci<ci0+128; ++ci) {
    const float v = rpn[(size_t)ci*HW + hw];
#pragma unroll
    for (int c=0;c<18;c++) accA[c] = fmaf(v, cw[c*CMID+ci], accA[c]);
#pragma unroll
    for (int c=0;c<36;c++) accB[c] = fmaf(v, bw[c*CMID+ci], accB[c]);
  }
  float* p = partial + (size_t)cg*54*HW;
#pragma unroll
  for (int c=0;c<18;c++) p[(size_t)c*HW + hw] = accA[c];
#pragma unroll
  for (int c=0;c<36;c++) p[(size_t)(18+c)*HW + hw] = accB[c];
}

__global__ void conv1x1r(const float* __restrict__ partial,
    const float* __restrict__ cb, const float* __restrict__ bb,
    float* __restrict__ cls_out, float* __restrict__ bbox_out)
{
  const int o = blockIdx.x*256 + threadIdx.x;    // 54*HW total
  const int c = o / HW;
  const int hw = o - c*HW;
  float v = partial[o] + partial[(size_t)54*HW + o] + partial[(size_t)108*HW + o] + partial[(size_t)162*HW + o];
  if (c < 18) cls_out[(size_t)c*HW + hw] = v + cb[c];
  else        bbox_out[(size_t)(c-18)*HW + hw] = v + bb[c-18];
}

// ---------------- K3: scores (softmax fg), keys, histogram, decode+clip ----------------
__global__ void score_decode(const float* __restrict__ cls_out,
    const float* __restrict__ bbox_out, const float* __restrict__ im_info,
    u64* __restrict__ keys, float4* __restrict__ props, u32* __restrict__ hist)
{
#pragma clang fp contract(off)
  const int n = blockIdx.x*256 + threadIdx.x;
  const int hw = n / 9;
  const int a  = n - hw*9;
  const int x = hw % HF, y = hw / HF;
  const float l0 = cls_out[a*HW + hw];
  const float l1 = cls_out[(9+a)*HW + hw];
  const float m = fmaxf(l0, l1);
  const float e0 = expf(l0 - m), e1 = expf(l1 - m);
  const float s = e1 / (e0 + e1);
  const u32 sb = __float_as_uint(s);      // s >= 0 -> bits monotone
  keys[n] = ((u64)(~sb) << 32) | (u32)n;  // asc key == desc score, tie -> asc idx
  atomicAdd(&hist[sb >> 16], 1u);

  const float ax1 = BA[a][0] + 16.f*(float)x;
  const float ay1 = BA[a][1] + 16.f*(float)y;
  const float ax2 = BA[a][2] + 16.f*(float)x;
  const float ay2 = BA[a][3] + 16.f*(float)y;
  const float aw = ax2 - ax1 + 1.f, ah = ay2 - ay1 + 1.f;
  const float cx = ax1 + 0.5f*aw,  cy = ay1 + 0.5f*ah;
  const float d0 = bbox_out[(a*4+0)*HW + hw];
  const float d1 = bbox_out[(a*4+1)*HW + hw];
  const float d2 = bbox_out[(a*4+2)*HW + hw];
  const float d3 = bbox_out[(a*4+3)*HW + hw];
  const float pcx = d0*aw + cx, pcy = d1*ah + cy;
  const float pw = expf(d2)*aw, ph = expf(d3)*ah;
  const float imh = im_info[0], imw = im_info[1];
  float bx1 = fminf(fmaxf(pcx - 0.5f*pw, 0.f), imw - 1.f);
  float by1 = fminf(fmaxf(pcy - 0.5f*ph, 0.f), imh - 1.f);
  float bx2 = fminf(fmaxf(pcx + 0.5f*pw, 0.f), imw - 1.f);
  float by2 = fminf(fmaxf(pcy + 0.5f*ph, 0.f), imh - 1.f);
  props[n] = make_float4(bx1, by1, bx2, by2);
}

// ---------------- K4: find threshold bucket ----------------
__global__ void hist_scan(const u32* __restrict__ hist, u32* __restrict__ thresh)
{
  __shared__ u32 csum[1024];
  const int t = threadIdx.x;
  u32 s = 0;
  for (int i=0;i<64;i++) s += hist[t*64+i];
  csum[t] = s;
  __syncthreads();
  if (t == 0) {
    u32 cum = 0;
    int tc = 1023;
    for (; tc >= 0; --tc) {
      if (cum + csum[tc] >= PRE) break;
      cum += csum[tc];
    }
    u32 b = (u32)tc*64u + 63u;
    for (;;) { cum += hist[b]; if (cum >= PRE) break; --b; }
    thresh[0] = b;
  }
}

// ---------------- K5: compact candidates ----------------
__global__ void collect_cand(const u64* __restrict__ keys, const u32* __restrict__ thresh,
                             u32* __restrict__ counter, u64* __restrict__ cand)
{
  const int n = blockIdx.x*256 + threadIdx.x;
  const u64 k = keys[n];
  const u32 sb = ~(u32)(k >> 32);
  if ((sb >> 16) >= thresh[0]) {
    u32 p = atomicAdd(counter, 1u);
    cand[p] = k;
  }
}

// ---------------- K6: exact rank among candidates -> scatter sorted boxes ----------------
__global__ void rank_scatter(const u64* __restrict__ cand, const u32* __restrict__ counter,
                             const float4* __restrict__ props, float4* __restrict__ sprops)
{
  __shared__ u64 sk[256];
  const int M = (int)counter[0];
  if (blockIdx.x*256 >= M) return;        // block-uniform
  const int i = blockIdx.x*256 + threadIdx.x;
  const u64 key = (i < M) ? cand[i] : ~0ull;
  int rank = 0;
  for (int t0 = 0; t0 < M; t0 += 256) {
    const int j = t0 + threadIdx.x;
    sk[threadIdx.x] = (j < M) ? cand[j] : ~0ull;
    __syncthreads();
#pragma unroll 8
    for (int k=0;k<256;k++) rank += (sk[k] < key) ? 1 : 0;
    __syncthreads();
  }
  if (i < M && rank < PRE) sprops[rank] = props[(u32)key];
}

// ---------------- K7: NMS suppression bitmask ----------------
__global__ void nms_mask(const float4* __restrict__ sp, u64* __restrict__ mask)
{
#pragma clang fp contract(off)
  __shared__ float4 cb[64];
  __shared__ float  ca[64];
  const int c0 = blockIdx.x * 64;
  const int cend = min(64, PRE - c0);
  if ((int)threadIdx.x < cend) {
    float4 b = sp[c0 + threadIdx.x];
    cb[threadIdx.x] = b;
    ca[threadIdx.x] = (b.z-b.x+1.f)*(b.w-b.y+1.f);
  }
  __syncthreads();
  const int row = blockIdx.y*64 + threadIdx.x;
  if (row >= PRE) return;
  const float4 rb = sp[row];
  const float ra = (rb.z-rb.x+1.f)*(rb.w-rb.y+1.f);
  u64 bits = 0;
  for (int j=0;j<cend;j++) {
    const float4 c = cb[j];
    const float xx1 = fmaxf(rb.x, c.x), yy1 = fmaxf(rb.y, c.y);
    const float xx2 = fminf(rb.z, c.z), yy2 = fminf(rb.w, c.w);
    const float inter = fmaxf(xx2-xx1+1.f, 0.f) * fmaxf(yy2-yy1+1.f, 0.f);
    const float iou = inter / (ra + ca[j] - inter);
    if (iou > 0.7f) bits |= (1ull << j);
  }
  mask[(size_t)row*NW + blockIdx.x] = bits;
}

// ---------------- K8: serial greedy scan (one wave) -> rois ----------------
// lanes 0..46 own 4 contiguous words each (2x dwordx4 loads); consumed words skip loads.
__global__ void nms_scan(const u64* __restrict__ mask, const float4* __restrict__ sp,
                         float* __restrict__ rois)
{
  __shared__ int keep_s[POST];
  const int l = threadIdx.x;
  u64 v[4];
#pragma unroll
  for (int q=0;q<4;q++) {
    const int w = l*4+q;
    u64 val = 0;
    if (w < NW) { val = ~0ull; if (w == NW-1) val = (1ull<<32) - 1ull; }
    v[q] = val;
  }
  for (int it=0; it<POST; ++it) {
    const u64 nz = (v[0]|v[1]) | (v[2]|v[3]);
    const u64 bal = __ballot(nz != 0);
    int idx = -1;
    if (bal != 0) {
      const int src = __ffsll((unsigned long long)bal) - 1;
      int fi = 0;
      if (v[0])      fi = (l*4+0)*64 + __ffsll(v[0]) - 1;
      else if (v[1]) fi = (l*4+1)*64 + __ffsll(v[1]) - 1;
      else if (v[2]) fi = (l*4+2)*64 + __ffsll(v[2]) - 1;
      else if (v[3]) fi = (l*4+3)*64 + __ffsll(v[3]) - 1;
      idx = __shfl(fi, src);
    }
    if (l == 0) keep_s[it] = (idx < 0) ? 0 : idx;
    if (idx >= 0 && nz != 0) {
      const u64* mrow = mask + (size_t)idx*NW + l*4;   // lanes with nz!=0 have l*4+3 < NW
      v[0] &= ~mrow[0]; v[1] &= ~mrow[1]; v[2] &= ~mrow[2]; v[3] &= ~mrow[3];
    }
  }
  __syncthreads();
  for (int i = l; i < POST; i += 64) {
    const float4 b = sp[keep_s[i]];
    rois[i*5+0] = 0.f;
    rois[i*5+1] = b.x; rois[i*5+2] = b.y; rois[i*5+3] = b.z; rois[i*5+4] = b.w;
  }
}

// ---------------- K9/K10: ROI bilinear crop ----------------
struct __align__(16) Samp { int p0,p1,p2,p3; float w0,w1,w2,w3; };

__global__ void roi_table(const float* __restrict__ rois, Samp* __restrict__ tab)
{
#pragma clang fp contract(off)
  const int idx = blockIdx.x*256 + threadIdx.x;
  if (idx >= POST*49) return;
  const int r = idx / 49;
  const int s = idx - r*49;
  const int py = s / 7, px = s - py*7;
  const float x1 = rois[r*5+1] * 0.0625f;
  const float y1 = rois[r*5+2] * 0.0625f;
  const float x2 = rois[r*5+3] * 0.0625f;
  const float y2 = rois[r*5+4] * 0.0625f;
  const float t00 = (x2-x1)/95.f;
  const float t02 = (x1+x2-95.f)/95.f;
  const float t11 = (y2-y1)/95.f;
  const float t12 = (y1+y2-95.f)/95.f;
  const float lx = (float)(px-3)/3.f;
  const float ly = (float)(py-3)/3.f;
  const float gx = t00*lx + t02;
  const float gy = t11*ly + t12;
  const float ix = (gx+1.f)*0.5f*95.f;
  const float iy = (gy+1.f)*0.5f*95.f;
  const float ix0 = floorf(ix), iy0 = floorf(iy);
  const float wx = ix-ix0, wy = iy-iy0;
  const float xs[2] = {ix0, ix0+1.f};
  const float ys[2] = {iy0, iy0+1.f};
  const float wxs[2] = {1.f-wx, wx};
  const float wys[2] = {1.f-wy, wy};
  int pos[4]; float wt[4];
#pragma unroll
  for (int k=0;k<4;k++) {
    const int dy = k>>1, dx = k&1;
    const float yi = ys[dy], xi = xs[dx];
    const bool valid = (yi>=0.f)&&(yi<96.f)&&(xi>=0.f)&&(xi<96.f);
    const int yc = (int)fminf(fmaxf(yi,0.f),95.f);
    const int xc = (int)fminf(fmaxf(xi,0.f),95.f);
    pos[k] = yc*96+xc;
    wt[k] = wys[dy]*wxs[dx] * (valid?1.f:0.f);
  }
  Samp t;
  t.p0=pos[0]; t.p1=pos[1]; t.p2=pos[2]; t.p3=pos[3];
  t.w0=wt[0];  t.w1=wt[1];  t.w2=wt[2];  t.w3=wt[3];
  tab[idx] = t;
}

__global__ void roi_pool(const float* __restrict__ feat, const Samp* __restrict__ tab,
                         float* __restrict__ out)
{
#pragma clang fp contract(off)
  const int o = blockIdx.x*256 + threadIdx.x;   // grid exact: OUT_POOL/256
  const int s  = o % 49;
  const int rc = o / 49;
  const int c = rc & (CIN-1);
  const int r = rc >> 10;
  const Samp t = tab[r*49+s];
  const float* f = feat + (size_t)c*HW;
  out[o] = t.w0*f[t.p0] + t.w1*f[t.p1] + t.w2*f[t.p2] + t.w3*f[t.p3];
}

// ---------------- K11: anchor-gt IoU matrix (masked) + per-gt max ----------------
__global__ void anchor_ov(const float* __restrict__ gt, const float* __restrict__ im_info,
                          float* __restrict__ ov, u32* __restrict__ gtmax)
{
#pragma clang fp contract(off)
  __shared__ u32 lmax[8];
  if (threadIdx.x < 8) lmax[threadIdx.x] = 0u;
  __syncthreads();
  const int n = blockIdx.x*256 + threadIdx.x;
  const int hw = n/9, a = n - hw*9;
  const int x = hw % HF, y = hw / HF;
  const float ax1 = BA[a][0]+16.f*(float)x, ay1 = BA[a][1]+16.f*(float)y;
  const float ax2 = BA[a][2]+16.f*(float)x, ay2 = BA[a][3]+16.f*(float)y;
  const float imh = im_info[0], imw = im_info[1];
  const bool inside = (ax1 >= 0.f) && (ay1 >= 0.f) && (ax2 < imw) && (ay2 < imh);
  const float aa = (ax2-ax1+1.f)*(ay2-ay1+1.f);
#pragma unroll
  for (int j=0;j<8;j++) {
    const float g0=gt[j*5+0], g1=gt[j*5+1], g2=gt[j*5+2], g3=gt[j*5+3];
    const float ga = (g2-g0+1.f)*(g3-g1+1.f);
    const float xx1 = fmaxf(ax1,g0), yy1 = fmaxf(ay1,g1);
    const float xx2 = fminf(ax2,g2), yy2 = fminf(ay2,g3);
    const float inter = fmaxf(xx2-xx1+1.f,0.f)*fmaxf(yy2-yy1+1.f,0.f);
    const float iou = inter/(aa+ga-inter);
    const float o = inside ? iou : -1.f;
    ov[(size_t)n*8+j] = o;
    atomicMax(&lmax[j], fkey(o));
  }
  __syncthreads();
  if (threadIdx.x < 8) atomicMax(&gtmax[threadIdx.x], lmax[threadIdx.x]);
}

// ---------------- K12: labels + argmax + ex-count partials ----------------
__global__ void anchor_label(const float* __restrict__ ov, const u32* __restrict__ gtmax,
                             signed char* __restrict__ labels, signed char* __restrict__ amax,
                             int* __restrict__ exP)
{
  __shared__ int se[256];
  const int n = blockIdx.x*256 + threadIdx.x;
  float best = -3.402823466e38f;
  int arg = 0;
  bool isbest = false;
#pragma unroll
  for (int j=0;j<8;j++) {
    const float o = ov[(size_t)n*8+j];
    if (o > best) { best = o; arg = j; }
    if (fkey(o) == gtmax[j]) isbest = true;
  }
  const bool inside = ov[(size_t)n*8+0] >= 0.f;
  int lab = -1;
  if (inside && best < 0.3f) lab = 0;
  if (inside && isbest) lab = 1;
  if (inside && best >= 0.7f) lab = 1;
  labels[n] = (signed char)lab;
  amax[n] = (signed char)arg;
  se[threadIdx.x] = (lab >= 0) ? 1 : 0;
  __syncthreads();
  for (int s=128; s>0; s>>=1) {
    if ((int)threadIdx.x < s) se[threadIdx.x] += se[threadIdx.x+s];
    __syncthreads();
  }
  if (threadIdx.x==0) exP[blockIdx.x] = se[0];
}

// ---------------- K13: per-anchor loss terms -> block partials ----------------
__global__ void loss_partial(const float* __restrict__ cls_out, const float* __restrict__ bbox_out,
                             const float* __restrict__ gt, const signed char* __restrict__ labels,
                             const signed char* __restrict__ amax, float2* __restrict__ lossP)
{
#pragma clang fp contract(off)
  __shared__ float sce[256];
  __shared__ float sbx[256];
  const int n = blockIdx.x*256 + threadIdx.x;
  const int hw = n/9, a = n - hw*9;
  const int lab = labels[n];
  float ce = 0.f, bx = 0.f;
  if (lab >= 0) {
    const float l0 = cls_out[a*HW+hw], l1 = cls_out[(9+a)*HW+hw];
    const float m = fmaxf(l0,l1);
    const float lse = m + logf(expf(l0-m)+expf(l1-m));
    ce = lse - (lab==1 ? l1 : l0);
  }
  if (lab == 1) {
    const int x = hw % HF, y = hw / HF;
    const float ax1 = BA[a][0]+16.f*(float)x, ay1 = BA[a][1]+16.f*(float)y;
    const float ax2 = BA[a][2]+16.f*(float)x, ay2 = BA[a][3]+16.f*(float)y;
    const float ew = ax2-ax1+1.f, eh = ay2-ay1+1.f;
    const float ecx = ax1+0.5f*ew, ecy = ay1+0.5f*eh;
    const int g = amax[n];
    const float g0=gt[g*5+0], g1=gt[g*5+1], g2=gt[g*5+2], g3=gt[g*5+3];
    const float gw = g2-g0+1.f, gh = g3-g1+1.f;
    const float gcx = g0+0.5f*gw, gcy = g1+0.5f*gh;
    float tgt[4];
    tgt[0] = (gcx-ecx)/ew;
    tgt[1] = (gcy-ecy)/eh;
    tgt[2] = logf(gw/ew);
    tgt[3] = logf(gh/eh);
#pragma unroll
    for (int j=0;j<4;j++) {
      const float d = bbox_out[(a*4+j)*HW+hw];
      const float diff = d - tgt[j];
      const float ad = fabsf(diff);
      bx += (ad < (1.0f/9.0f)) ? (4.5f*diff*diff) : (ad - 0.5f/9.0f);
    }
  }
  sce[threadIdx.x]=ce; sbx[threadIdx.x]=bx;
  __syncthreads();
  for (int s=128;s>0;s>>=1) {
    if ((int)threadIdx.x<s) { sce[threadIdx.x]+=sce[threadIdx.x+s]; sbx[threadIdx.x]+=sbx[threadIdx.x+s]; }
    __syncthreads();
  }
  if (threadIdx.x==0) lossP[blockIdx.x] = make_float2(sce[0], sbx[0]);
}

// ---------------- K14: final fixed-order reduction -> losses ----------------
__global__ void loss_final(const float2* __restrict__ lossP, const int* __restrict__ exP,
                           float* __restrict__ out)
{
  __shared__ float a[512];
  __shared__ float c[512];
  __shared__ int   e[512];
  const int t = threadIdx.x;
  float2 v = (t < NBLK) ? lossP[t] : make_float2(0.f,0.f);
  int ev = (t < NBLK) ? exP[t] : 0;
  a[t]=v.x; c[t]=v.y; e[t]=ev;
  __syncthreads();
  for (int s=256;s>0;s>>=1) {
    if (t<s) { a[t]+=a[t+s]; c[t]+=c[t+s]; e[t]+=e[t+s]; }
    __syncthreads();
  }
  if (t==0) {
    const float nex = (float)max(e[0], 1);
    out[OUT_POOL+0] = a[0] / nex;
    out[OUT_POOL+1] = c[0] / nex;
  }
}

// ---------------- launcher ----------------
extern "C" void kernel_launch(void* const* d_in, const int* in_sizes, int n_in,
                              void* d_out, int out_size, void* d_ws, size_t ws_size,
                              hipStream_t stream)
{
  const float* feat    = (const float*)d_in[0];
  const float* gt      = (const float*)d_in[1];
  const float* im_info = (const float*)d_in[2];
  const float* rpn_w   = (const float*)d_in[3];
  const float* rpn_b   = (const float*)d_in[4];
  const float* cls_w   = (const float*)d_in[5];
  const float* cls_b   = (const float*)d_in[6];
  const float* bbox_w  = (const float*)d_in[7];
  const float* bbox_b  = (const float*)d_in[8];
  float* out = (float*)d_out;
  char* ws = (char*)d_ws;

  size_t off = 0;
  auto alloc = [&](size_t bytes) {
    size_t o = off;
    off = (off + bytes + 255) & ~(size_t)255;
    return o;
  };
  // zero-region (memset every call)
  size_t o_counter = alloc(4);
  size_t o_gtmax   = alloc(32);
  size_t o_thresh  = alloc(4);
  size_t o_hist    = alloc(65536*4);
  size_t zeroBytes = off;
  // persistent across phases
  size_t o_cls  = alloc((size_t)18*HW*4);
  size_t o_bbox = alloc((size_t)36*HW*4);
  size_t o_rpn  = alloc((size_t)CMID*HW*4);
  // overlapped region R:
  //   phase A: img (39.3 MB) + wbuf (18.9 MB)           [conv inputs]
  //   phase B: partial (8.15 MB, overlaps dead img)      [1x1 partials]
  //   phase C: proposal/loss scratch (overlaps dead img/partial/wbuf)
  size_t o_R = off;
  size_t o_img  = o_R;
  size_t o_wbuf = o_R + 39337984;
  size_t o_partial = o_R;                 // after conv done, img dead
  size_t coff = o_R;
  auto calloc2 = [&](size_t bytes) {
    size_t o = coff;
    coff = (coff + bytes + 255) & ~(size_t)255;
    return o;
  };
  size_t o_keys   = calloc2((size_t)NA*8);
  size_t o_props  = calloc2((size_t)NA*16);
  size_t o_cand   = calloc2((size_t)NA*8);
  size_t o_sprops = calloc2((size_t)PRE*16);
  size_t o_mask   = calloc2((size_t)PRE*NW*8);
  size_t o_rois   = calloc2((size_t)POST*5*4);
  size_t o_tab    = calloc2((size_t)POST*49*sizeof(Samp));
  size_t o_ov     = calloc2((size_t)NA*8*4);
  size_t o_lab    = calloc2((size_t)NA);
  size_t o_amax   = calloc2((size_t)NA);
  size_t o_exP    = calloc2((size_t)NBLK*4);
  size_t o_lossP  = calloc2((size_t)NBLK*8);
  (void)ws_size; (void)in_sizes; (void)n_in; (void)out_size;

  hipMemsetAsync(ws, 0, zeroBytes, stream);

  f16x8* img      = (f16x8*)(ws + o_img);
  f16x8* wbuf     = (f16x8*)(ws + o_wbuf);
  float* partial  = (float*)(ws + o_partial);
  float* rpn      = (float*)(ws + o_rpn);
  float* cls_out  = (float*)(ws + o_cls);
  float* bbox_out = (float*)(ws + o_bbox);
  u64*   keys     = (u64*)(ws + o_keys);
  float4* props   = (float4*)(ws + o_props);
  u64*   cand     = (u64*)(ws + o_cand);
  float4* sprops  = (float4*)(ws + o_sprops);
  u64*   maskp    = (u64*)(ws + o_mask);
  float* rois     = (float*)(ws + o_rois);
  Samp*  tab      = (Samp*)(ws + o_tab);
  float* ovp      = (float*)(ws + o_ov);
  signed char* labels = (signed char*)(ws + o_lab);
  signed char* amax   = (signed char*)(ws + o_amax);
  int*    exP     = (int*)(ws + o_exP);
  float2* lossP   = (float2*)(ws + o_lossP);
  u32* counter    = (u32*)(ws + o_counter);
  u32* gtmaxp     = (u32*)(ws + o_gtmax);
  u32* thresh     = (u32*)(ws + o_thresh);
  u32* hist       = (u32*)(ws + o_hist);

  // phase A: conv via split-fp16 MFMA
  prep_img<<<dim3(98,32), 256, 0, stream>>>(feat, img);
  prep_w<<<256, 256, 0, stream>>>(rpn_w, wbuf);
  rpn_conv_mfma<<<dim3(2,96,8), 64, 0, stream>>>(img, wbuf, rpn_b, rpn);
  // phase B: 1x1 convs (partial overlaps dead img region)
  conv1x1p<<<dim3(144,4), 64, 0, stream>>>(rpn, cls_w, bbox_w, partial);
  conv1x1r<<<54*HW/256, 256, 0, stream>>>(partial, cls_b, bbox_b, cls_out, bbox_out);
  // phase C: proposals (reuses region R — stream-ordered after phase B)
  score_decode<<<NBLK, 256, 0, stream>>>(cls_out, bbox_out, im_info, keys, props, hist);
  hist_scan<<<1, 1024, 0, stream>>>(hist, thresh);
  collect_cand<<<NBLK, 256, 0, stream>>>(keys, thresh, counter, cand);
  rank_scatter<<<NBLK, 256, 0, stream>>>(cand, counter, props, sprops);
  nms_mask<<<dim3(NW, NW), 64, 0, stream>>>(sprops, maskp);
  nms_scan<<<1, 64, 0, stream>>>(maskp, sprops, rois);
  roi_table<<<(POST*49+255)/256, 256, 0, stream>>>(rois, tab);
  roi_pool<<<OUT_POOL/256, 256, 0, stream>>>(feat, tab, out);
  // loss path
  anchor_ov<<<NBLK, 256, 0, stream>>>(gt, im_info, ovp, gtmaxp);
  anchor_label<<<NBLK, 256, 0, stream>>>(ovp, gtmaxp, labels, amax, exP);
  loss_partial<<<NBLK, 256, 0, stream>>>(cls_out, bbox_out, gt, labels, amax, lossP);
  loss_final<<<1, 512, 0, stream>>>(lossP, exP, out);
}

// Round 5
// 900.876 us; speedup vs baseline: 3.1180x; 1.2546x over previous
//
#include <hip/hip_runtime.h>
#include <stdint.h>

typedef unsigned int u32;
typedef unsigned long long u64;
typedef _Float16 f16x8 __attribute__((ext_vector_type(8)));
typedef float f32x4 __attribute__((ext_vector_type(4)));

#define HF 96
#define HW 9216           // 96*96
#define CIN 1024
#define CMID 512
#define NA 82944          // HW*9
#define PRE 12000
#define POST 300
#define NW 188            // ceil(PRE/64)
#define NBLK 324          // NA/256
#define OUT_POOL (POST*CIN*49)

// base anchors, exact per np.round (banker's) of the reference generator
__device__ __constant__ float BA[9][4] = {
  {-84.f,-40.f,99.f,55.f}, {-176.f,-88.f,191.f,103.f}, {-360.f,-184.f,375.f,199.f},
  {-56.f,-56.f,71.f,71.f}, {-120.f,-120.f,135.f,135.f}, {-248.f,-248.f,263.f,263.f},
  {-36.f,-80.f,51.f,95.f}, {-80.f,-168.f,95.f,183.f},  {-168.f,-344.f,183.f,359.f}
};

__device__ __forceinline__ u32 fkey(float f) {
  u32 u = __float_as_uint(f);
  return (u & 0x80000000u) ? ~u : (u | 0x80000000u);
}

__device__ __forceinline__ void gl_lds16(const void* g, void* l) {
  __builtin_amdgcn_global_load_lds((const __attribute__((address_space(1))) void*)g,
                                   (__attribute__((address_space(3))) void*)l, 16, 0, 0);
}

// ---------------- P1: feat -> swizzled fp16 hi/lo image with halo (coalesced) ----------------
__global__ void prep_img(const float* __restrict__ feat, f16x8* __restrict__ img)
{
  __shared__ float ls[32][100];
  const int yy = blockIdx.x;
  const int kt = blockIdx.y;
  const int tid = threadIdx.x;
  const int y = yy - 1;
  const bool yok = (unsigned)y < 96u;
  if (yok) {
    for (int e = tid; e < 3072; e += 256) {
      const int ci = e / 96;
      const int x = e - ci * 96;
      ls[ci][x] = feat[(size_t)(kt*32 + ci)*HW + y*96 + x];
    }
  }
  __syncthreads();
  for (int idx = tid; idx < 784; idx += 256) {
    const int col = idx >> 3;
    const int q = idx & 7;
    const int x = col - 1;
    f16x8 val;
#pragma unroll
    for (int i=0;i<8;i++) val[i] = (_Float16)0.f;
    if (yok && (unsigned)x < 96u) {
#pragma unroll
      for (int i=0;i<8;i++) {
        const float v = ls[(q&3)*8 + i][x];
        if (q < 4) val[i] = (_Float16)v;
        else { const _Float16 hi = (_Float16)v; val[i] = (_Float16)((v - (float)hi)*1024.f); }
      }
    }
    const int sw = (col + 2*y) & 7;
    img[(size_t)((kt*98 + yy)*98 + col)*8 + (q ^ sw)] = val;
  }
}

// ---------------- P2: weights -> frag-ready hi/lo (x64 pre-scale), kt-major ----------------
__global__ void prep_w(const float* __restrict__ w, f16x8* __restrict__ wbuf)
{
  const int t = blockIdx.x*256 + threadIdx.x;   // 65536 total
  const int co = t & 511;
  const int cic = t >> 9;                        // 0..127
  const int kt = cic >> 2;
  const int kg = cic & 3;
  const float* wp = w + (size_t)co*9216 + cic*72;
#pragma unroll
  for (int tap=0; tap<9; ++tap) {
    f16x8 hv, lv;
#pragma unroll
    for (int i=0;i<8;i++) {
      const float v = wp[i*9 + tap] * 64.f;
      const _Float16 hi = (_Float16)v;
      hv[i] = hi;
      lv[i] = (_Float16)((v - (float)hi)*1024.f);
    }
    wbuf[(size_t)(((kt*9 + tap)*2 + 0)*4 + kg)*512 + co] = hv;
    wbuf[(size_t)(((kt*9 + tap)*2 + 1)*4 + kg)*512 + co] = lv;
  }
}

// ---------------- K1: 3x3 conv, 4-wave blocks, double-buffered 2-phase ----------------
// block 256 thr; tile 128co x 48px (wave w: co 32); grid (2,96,4)=768 = 3 blocks/CU.
__global__ __launch_bounds__(256, 3) void rpn_conv_mfma(
    const f16x8* __restrict__ img, const f16x8* __restrict__ wbuf,
    const float* __restrict__ bias, float* __restrict__ out)
{
  __shared__ f16x8 in_s[2560];   // 2 buffers x 1280 slots x 16B = 40960 B
  const int tid = threadIdx.x;
  const int lane = tid & 63;
  const int wv = tid >> 6;
  const int kgrp = lane >> 4;
  const int ln15 = lane & 15;
  const int x0 = blockIdx.x * 48;
  const int y  = blockIdx.y;
  const int co0 = blockIdx.z * 128 + wv * 32;

  int goff[5];
#pragma unroll
  for (int j=0;j<5;j++) {
    int s = j*256 + tid; if (s > 1199) s = 1199;
    const int row = s / 400;
    const int rem = s - row*400;
    goff[j] = ((y + row)*98 + x0 + (rem>>3))*8 + (rem & 7);
  }
  const int ldst0 = wv*64;

  int keyb[3];
#pragma unroll
  for (int pt=0; pt<3; ++pt) keyb[pt] = x0 + pt*16 + ln15 + 1 + 2*y;

  f32x4 acc1[2][3], acc2[2][3];
#pragma unroll
  for (int c=0;c<2;c++)
#pragma unroll
    for (int pt=0;pt<3;pt++) {
      acc1[c][pt] = (f32x4){0.f,0.f,0.f,0.f};
      acc2[c][pt] = (f32x4){0.f,0.f,0.f,0.f};
    }

  const int wlane = kgrp*512 + co0 + ln15;

  // prologue: stage kt=0 into buffer 0
#pragma unroll
  for (int j=0;j<5;j++) gl_lds16(img + goff[j], in_s + j*256 + ldst0);
  asm volatile("s_waitcnt vmcnt(0)" ::: "memory");
  __syncthreads();

  for (int kt = 0; kt < 32; ++kt) {
    const int cur = (kt & 1) * 1280;
    if (kt < 31) {
      const f16x8* kb = img + (size_t)(kt+1)*76832;
#pragma unroll
      for (int j=0;j<5;j++) gl_lds16(kb + goff[j], in_s + (1280 - cur) + j*256 + ldst0);
    }
    const f16x8* bs = in_s + cur;
#pragma unroll
    for (int t=0; t<9; ++t) {
      const int dy = t/3 - 1, dx = t%3 - 1;
      f16x8 af[2][2];
#pragma unroll
      for (int h=0;h<2;h++) {
        const size_t wb = (size_t)(((kt*9 + t)*2 + h)*2048) + wlane;
#pragma unroll
        for (int c=0;c<2;c++) af[c][h] = wbuf[wb + c*16];
      }
      f16x8 bf[3][2];
#pragma unroll
      for (int pt=0;pt<3;pt++) {
        const int key = (keyb[pt] + dx + 2*dy) & 7;
        const int base = ((dy+1)*50 + pt*16 + ln15 + dx + 1)*8;
#pragma unroll
        for (int h=0;h<2;h++)
          bf[pt][h] = bs[base + ((h*4 + kgrp) ^ key)];
      }
#pragma unroll
      for (int c=0;c<2;c++)
#pragma unroll
        for (int pt=0;pt<3;pt++) {
          acc1[c][pt] = __builtin_amdgcn_mfma_f32_16x16x32_f16(af[c][0], bf[pt][0], acc1[c][pt], 0,0,0);
          acc2[c][pt] = __builtin_amdgcn_mfma_f32_16x16x32_f16(af[c][0], bf[pt][1], acc2[c][pt], 0,0,0);
          acc2[c][pt] = __builtin_amdgcn_mfma_f32_16x16x32_f16(af[c][1], bf[pt][0], acc2[c][pt], 0,0,0);
        }
    }
    asm volatile("s_waitcnt vmcnt(0)" ::: "memory");
    __syncthreads();
  }

  const int pixb = y*96 + x0;
#pragma unroll
  for (int c=0;c<2;c++) {
#pragma unroll
    for (int i=0;i<4;i++) {
      const int co = co0 + c*16 + kgrp*4 + i;
      const float bb = bias[co];
#pragma unroll
      for (int pt=0;pt<3;pt++) {
        const float v = (acc1[c][pt][i] + acc2[c][pt][i]*(1.f/1024.f))*(1.f/64.f) + bb;
        out[(size_t)co*HW + pixb + pt*16 + ln15] = v > 0.f ? v : 0.f;
      }
    }
  }
}

// ---------------- K2: 1x1 convs — ci-split partials + deterministic reduce ----------------
__global__ void conv1x1p(const float* __restrict__ rpn,
    const float* __restrict__ cw, const float* __restrict__ bw,
    float* __restrict__ partial)
{
  const int hw = blockIdx.x * 64 + threadIdx.x;
  const int cg = blockIdx.y;           // 0..3
  const int ci0 = cg * 128;
  float accA[18], accB[36];
#pragma unroll
  for (int c=0;c<18;c++) accA[c]=0.f;
#pragma unroll
  for (int c=0;c<36;c++) accB[c]=0.f;
  for (int ci=ci0; ci<ci0+128; ++ci) {
    const float v = rpn[(size_t)ci*HW + hw];
#pragma unroll
    for (int c=0;c<18;c++) accA[c] = fmaf(v, cw[c*CMID+ci], accA[c]);
#pragma unroll
    for (int c=0;c<36;c++) accB[c] = fmaf(v, bw[c*CMID+ci], accB[c]);
  }
  float* p = partial + (size_t)cg*54*HW;
#pragma unroll
  for (int c=0;c<18;c++) p[(size_t)c*HW + hw] = accA[c];
#pragma unroll
  for (int c=0;c<36;c++) p[(size_t)(18+c)*HW + hw] = accB[c];
}

__global__ void conv1x1r(const float* __restrict__ partial,
    const float* __restrict__ cb, const float* __restrict__ bb,
    float* __restrict__ cls_out, float* __restrict__ bbox_out)
{
  const int o = blockIdx.x*256 + threadIdx.x;    // 54*HW total
  const int c = o / HW;
  const int hw = o - c*HW;
  float v = partial[o] + partial[(size_t)54*HW + o] + partial[(size_t)108*HW + o] + partial[(size_t)162*HW + o];
  if (c < 18) cls_out[(size_t)c*HW + hw] = v + cb[c];
  else        bbox_out[(size_t)(c-18)*HW + hw] = v + bb[c-18];
}

// ---------------- transpose feat [C][HW] -> featT [HW][C] ----------------
__global__ void transpose_feat(const float* __restrict__ feat, float* __restrict__ featT)
{
  __shared__ float t[64][65];
  const int tid = threadIdx.x;
  const int bxhw = blockIdx.x*64, byc = blockIdx.y*64;
  const int l = tid & 63, g = tid >> 6;
#pragma unroll
  for (int i=0;i<16;i++) {
    const int cL = g + 4*i;
    t[cL][l] = feat[(size_t)(byc+cL)*HW + bxhw + l];
  }
  __syncthreads();
#pragma unroll
  for (int i=0;i<16;i++) {
    const int hwL = g + 4*i;
    featT[(size_t)(bxhw+hwL)*1024 + byc + l] = t[l][hwL];
  }
}

// ---------------- K3: scores, keys, LDS histogram (10-bit), decode+clip ----------------
__global__ void score_decode(const float* __restrict__ cls_out,
    const float* __restrict__ bbox_out, const float* __restrict__ im_info,
    u64* __restrict__ keys, float4* __restrict__ props, u32* __restrict__ hist10)
{
#pragma clang fp contract(off)
  __shared__ u32 h[1024];
  const int tid = threadIdx.x;
  for (int i=tid;i<1024;i+=256) h[i]=0;
  __syncthreads();
  const int n = blockIdx.x*256 + tid;
  const int hw = n / 9;
  const int a  = n - hw*9;
  const int x = hw % HF, y = hw / HF;
  const float l0 = cls_out[a*HW + hw];
  const float l1 = cls_out[(9+a)*HW + hw];
  const float m = fmaxf(l0, l1);
  const float e0 = expf(l0 - m), e1 = expf(l1 - m);
  const float s = e1 / (e0 + e1);
  const u32 sb = __float_as_uint(s);      // s >= 0 -> bits monotone
  keys[n] = ((u64)(~sb) << 32) | (u32)n;  // asc key == desc score, tie -> asc idx
  atomicAdd(&h[sb >> 22], 1u);

  const float ax1 = BA[a][0] + 16.f*(float)x;
  const float ay1 = BA[a][1] + 16.f*(float)y;
  const float ax2 = BA[a][2] + 16.f*(float)x;
  const float ay2 = BA[a][3] + 16.f*(float)y;
  const float aw = ax2 - ax1 + 1.f, ah = ay2 - ay1 + 1.f;
  const float cx = ax1 + 0.5f*aw,  cy = ay1 + 0.5f*ah;
  const float d0 = bbox_out[(a*4+0)*HW + hw];
  const float d1 = bbox_out[(a*4+1)*HW + hw];
  const float d2 = bbox_out[(a*4+2)*HW + hw];
  const float d3 = bbox_out[(a*4+3)*HW + hw];
  const float pcx = d0*aw + cx, pcy = d1*ah + cy;
  const float pw = expf(d2)*aw, ph = expf(d3)*ah;
  const float imh = im_info[0], imw = im_info[1];
  float bx1 = fminf(fmaxf(pcx - 0.5f*pw, 0.f), imw - 1.f);
  float by1 = fminf(fmaxf(pcy - 0.5f*ph, 0.f), imh - 1.f);
  float bx2 = fminf(fmaxf(pcx + 0.5f*pw, 0.f), imw - 1.f);
  float by2 = fminf(fmaxf(pcy + 0.5f*ph, 0.f), imh - 1.f);
  props[n] = make_float4(bx1, by1, bx2, by2);
  __syncthreads();
  for (int i=tid;i<1024;i+=256) if (h[i]) atomicAdd(&hist10[i], h[i]);
}

// ---------------- K4a: coarse threshold bucket ----------------
__global__ void hist_scan1(const u32* __restrict__ hist10, u32* __restrict__ meta)
{
  __shared__ u32 c[1024];
  const int t = threadIdx.x;
  c[t] = hist10[t];
  __syncthreads();
  if (t == 0) {
    u32 cum = 0;
    int b = 1023;
    for (; b > 0; --b) {
      if (cum + c[b] >= PRE) break;
      cum += c[b];
    }
    meta[0] = (u32)b;
    meta[1] = cum;
  }
}

// ---------------- K4b: refine within winning 10-bit bucket (64 sub-buckets) ----------------
__global__ void hist_refine(const u64* __restrict__ keys, const u32* __restrict__ meta,
                            u32* __restrict__ h64)
{
  __shared__ u32 h[64];
  const int tid = threadIdx.x;
  if (tid < 64) h[tid] = 0;
  __syncthreads();
  const int n = blockIdx.x*256 + tid;
  const u32 sb = ~(u32)(keys[n] >> 32);
  if ((sb >> 22) == meta[0]) atomicAdd(&h[(sb >> 16) & 63], 1u);
  __syncthreads();
  if (tid < 64 && h[tid]) atomicAdd(&h64[tid], h[tid]);
}

// ---------------- K4c: exact 16-bit threshold ----------------
__global__ void hist_scan2(const u32* __restrict__ h64, const u32* __restrict__ meta,
                           u32* __restrict__ thresh)
{
  u32 cum = meta[1];
  int s = 63;
  for (; s > 0; --s) { cum += h64[s]; if (cum >= PRE) break; }
  if (s == 0) cum += h64[0];
  thresh[0] = (meta[0] << 6) | (u32)s;
}

// ---------------- K5: compact candidates ----------------
__global__ void collect_cand(const u64* __restrict__ keys, const u32* __restrict__ thresh,
                             u32* __restrict__ counter, u64* __restrict__ cand)
{
  const int n = blockIdx.x*256 + threadIdx.x;
  const u64 k = keys[n];
  const u32 sb = ~(u32)(k >> 32);
  if ((sb >> 16) >= thresh[0]) {
    u32 p = atomicAdd(counter, 1u);
    cand[p] = k;
  }
}

// ---------------- K6: exact rank among candidates -> scatter sorted boxes ----------------
__global__ void rank_scatter(const u64* __restrict__ cand, const u32* __restrict__ counter,
                             const float4* __restrict__ props, float4* __restrict__ sprops)
{
  __shared__ u64 sk[256];
  const int M = (int)counter[0];
  if (blockIdx.x*256 >= M) return;        // block-uniform
  const int i = blockIdx.x*256 + threadIdx.x;
  const u64 key = (i < M) ? cand[i] : ~0ull;
  int rank = 0;
  for (int t0 = 0; t0 < M; t0 += 256) {
    const int j = t0 + threadIdx.x;
    sk[threadIdx.x] = (j < M) ? cand[j] : ~0ull;
    __syncthreads();
#pragma unroll 8
    for (int k=0;k<256;k++) rank += (sk[k] < key) ? 1 : 0;
    __syncthreads();
  }
  if (i < M && rank < PRE) sprops[rank] = props[(u32)key];
}

// ---------------- K7: NMS suppression bitmask (upper triangle only) ----------------
__global__ void nms_mask(const float4* __restrict__ sp, u64* __restrict__ mask)
{
#pragma clang fp contract(off)
  // lower-triangle words are never consulted meaningfully: when idx is selected
  // all valid-bits below idx are already 0, so garbage there ANDs into zeros.
  if (blockIdx.x*64 + 63 < blockIdx.y*64) return;
  __shared__ float4 cb[64];
  __shared__ float  ca[64];
  const int c0 = blockIdx.x * 64;
  const int cend = min(64, PRE - c0);
  if ((int)threadIdx.x < cend) {
    float4 b = sp[c0 + threadIdx.x];
    cb[threadIdx.x] = b;
    ca[threadIdx.x] = (b.z-b.x+1.f)*(b.w-b.y+1.f);
  }
  __syncthreads();
  const int row = blockIdx.y*64 + threadIdx.x;
  if (row >= PRE) return;
  const float4 rb = sp[row];
  const float ra = (rb.z-rb.x+1.f)*(rb.w-rb.y+1.f);
  u64 bits = 0;
  for (int j=0;j<cend;j++) {
    const float4 c = cb[j];
    const float xx1 = fmaxf(rb.x, c.x), yy1 = fmaxf(rb.y, c.y);
    const float xx2 = fminf(rb.z, c.z), yy2 = fminf(rb.w, c.w);
    const float inter = fmaxf(xx2-xx1+1.f, 0.f) * fmaxf(yy2-yy1+1.f, 0.f);
    const float iou = inter / (ra + ca[j] - inter);
    if (iou > 0.7f) bits |= (1ull << j);
  }
  mask[(size_t)row*NW + blockIdx.x] = bits;
}

// ---------------- K8: serial greedy scan (one wave) -> rois ----------------
__global__ void nms_scan(const u64* __restrict__ mask, const float4* __restrict__ sp,
                         float* __restrict__ rois)
{
  __shared__ int keep_s[POST];
  const int l = threadIdx.x;
  u64 v[4];
#pragma unroll
  for (int q=0;q<4;q++) {
    const int w = l*4+q;
    u64 val = 0;
    if (w < NW) { val = ~0ull; if (w == NW-1) val = (1ull<<32) - 1ull; }
    v[q] = val;
  }
  for (int it=0; it<POST; ++it) {
    const u64 nz = (v[0]|v[1]) | (v[2]|v[3]);
    const u64 bal = __ballot(nz != 0);
    int idx = -1;
    if (bal != 0) {
      const int src = __ffsll((unsigned long long)bal) - 1;
      int fi = 0;
      if (v[0])      fi = (l*4+0)*64 + __ffsll(v[0]) - 1;
      else if (v[1]) fi = (l*4+1)*64 + __ffsll(v[1]) - 1;
      else if (v[2]) fi = (l*4+2)*64 + __ffsll(v[2]) - 1;
      else if (v[3]) fi = (l*4+3)*64 + __ffsll(v[3]) - 1;
      idx = __shfl(fi, src);
    }
    if (l == 0) keep_s[it] = (idx < 0) ? 0 : idx;
    if (idx >= 0 && nz != 0) {
      const u64* mrow = mask + (size_t)idx*NW + l*4;
      v[0] &= ~mrow[0]; v[1] &= ~mrow[1]; v[2] &= ~mrow[2]; v[3] &= ~mrow[3];
    }
  }
  __syncthreads();
  for (int i = l; i < POST; i += 64) {
    const float4 b = sp[keep_s[i]];
    rois[i*5+0] = 0.f;
    rois[i*5+1] = b.x; rois[i*5+2] = b.y; rois[i*5+3] = b.z; rois[i*5+4] = b.w;
  }
}

// ---------------- K9/K10: ROI bilinear crop ----------------
struct __align__(16) Samp { int p0,p1,p2,p3; float w0,w1,w2,w3; };

__global__ void roi_table(const float* __restrict__ rois, Samp* __restrict__ tab)
{
#pragma clang fp contract(off)
  const int idx = blockIdx.x*256 + threadIdx.x;
  if (idx >= POST*49) return;
  const int r = idx / 49;
  const int s = idx - r*49;
  const int py = s / 7, px = s - py*7;
  const float x1 = rois[r*5+1] * 0.0625f;
  const float y1 = rois[r*5+2] * 0.0625f;
  const float x2 = rois[r*5+3] * 0.0625f;
  const float y2 = rois[r*5+4] * 0.0625f;
  const float t00 = (x2-x1)/95.f;
  const float t02 = (x1+x2-95.f)/95.f;
  const float t11 = (y2-y1)/95.f;
  const float t12 = (y1+y2-95.f)/95.f;
  const float lx = (float)(px-3)/3.f;
  const float ly = (float)(py-3)/3.f;
  const float gx = t00*lx + t02;
  const float gy = t11*ly + t12;
  const float ix = (gx+1.f)*0.5f*95.f;
  const float iy = (gy+1.f)*0.5f*95.f;
  const float ix0 = floorf(ix), iy0 = floorf(iy);
  const float wx = ix-ix0, wy = iy-iy0;
  const float xs[2] = {ix0, ix0+1.f};
  const float ys[2] = {iy0, iy0+1.f};
  const float wxs[2] = {1.f-wx, wx};
  const float wys[2] = {1.f-wy, wy};
  int pos[4]; float wt[4];
#pragma unroll
  for (int k=0;k<4;k++) {
    const int dy = k>>1, dx = k&1;
    const float yi = ys[dy], xi = xs[dx];
    const bool valid = (yi>=0.f)&&(yi<96.f)&&(xi>=0.f)&&(xi<96.f);
    const int yc = (int)fminf(fmaxf(yi,0.f),95.f);
    const int xc = (int)fminf(fmaxf(xi,0.f),95.f);
    pos[k] = yc*96+xc;
    wt[k] = wys[dy]*wxs[dx] * (valid?1.f:0.f);
  }
  Samp t;
  t.p0=pos[0]; t.p1=pos[1]; t.p2=pos[2]; t.p3=pos[3];
  t.w0=wt[0];  t.w1=wt[1];  t.w2=wt[2];  t.w3=wt[3];
  tab[idx] = t;
}

// coalesced: block (r, cblk of 256); featT is [HW][1024]
__global__ void roi_pool_coal(const float* __restrict__ featT, const Samp* __restrict__ tab,
                              float* __restrict__ out)
{
#pragma clang fp contract(off)
  __shared__ float st[49][257];
  const int tid = threadIdx.x;
  const int r = blockIdx.x, cb = blockIdx.y;
  const int c = cb*256 + tid;
  for (int s=0;s<49;s++) {
    const Samp t = tab[r*49+s];
    st[s][tid] = t.w0*featT[(size_t)t.p0*1024+c] + t.w1*featT[(size_t)t.p1*1024+c]
               + t.w2*featT[(size_t)t.p2*1024+c] + t.w3*featT[(size_t)t.p3*1024+c];
  }
  __syncthreads();
  float* ob = out + (size_t)r*50176 + cb*12544;
  for (int i=tid; i<12544; i+=256) {
    const int cL = i / 49, s = i - cL*49;
    ob[i] = st[s][cL];
  }
}

// fallback (gather) if workspace too small for featT
__global__ void roi_pool_gather(const float* __restrict__ feat, const Samp* __restrict__ tab,
                                float* __restrict__ out)
{
#pragma clang fp contract(off)
  const int o = blockIdx.x*256 + threadIdx.x;
  const int s  = o % 49;
  const int rc = o / 49;
  const int c = rc & (CIN-1);
  const int r = rc >> 10;
  const Samp t = tab[r*49+s];
  const float* f = feat + (size_t)c*HW;
  out[o] = t.w0*f[t.p0] + t.w1*f[t.p1] + t.w2*f[t.p2] + t.w3*f[t.p3];
}

// ---------------- K11: anchor-gt IoU matrix (masked) + per-gt max ----------------
__global__ void anchor_ov(const float* __restrict__ gt, const float* __restrict__ im_info,
                          float* __restrict__ ov, u32* __restrict__ gtmax)
{
#pragma clang fp contract(off)
  __shared__ u32 lmax[8];
  if (threadIdx.x < 8) lmax[threadIdx.x] = 0u;
  __syncthreads();
  const int n = blockIdx.x*256 + threadIdx.x;
  const int hw = n/9, a = n - hw*9;
  const int x = hw % HF, y = hw / HF;
  const float ax1 = BA[a][0]+16.f*(float)x, ay1 = BA[a][1]+16.f*(float)y;
  const float ax2 = BA[a][2]+16.f*(float)x, ay2 = BA[a][3]+16.f*(float)y;
  const float imh = im_info[0], imw = im_info[1];
  const bool inside = (ax1 >= 0.f) && (ay1 >= 0.f) && (ax2 < imw) && (ay2 < imh);
  const float aa = (ax2-ax1+1.f)*(ay2-ay1+1.f);
#pragma unroll
  for (int j=0;j<8;j++) {
    const float g0=gt[j*5+0], g1=gt[j*5+1], g2=gt[j*5+2], g3=gt[j*5+3];
    const float ga = (g2-g0+1.f)*(g3-g1+1.f);
    const float xx1 = fmaxf(ax1,g0), yy1 = fmaxf(ay1,g1);
    const float xx2 = fminf(ax2,g2), yy2 = fminf(ay2,g3);
    const float inter = fmaxf(xx2-xx1+1.f,0.f)*fmaxf(yy2-yy1+1.f,0.f);
    const float iou = inter/(aa+ga-inter);
    const float o = inside ? iou : -1.f;
    ov[(size_t)n*8+j] = o;
    atomicMax(&lmax[j], fkey(o));
  }
  __syncthreads();
  if (threadIdx.x < 8) atomicMax(&gtmax[threadIdx.x], lmax[threadIdx.x]);
}

// ---------------- K12: labels + argmax + ex-count partials ----------------
__global__ void anchor_label(const float* __restrict__ ov, const u32* __restrict__ gtmax,
                             signed char* __restrict__ labels, signed char* __restrict__ amax,
                             int* __restrict__ exP)
{
  __shared__ int se[256];
  const int n = blockIdx.x*256 + threadIdx.x;
  float best = -3.402823466e38f;
  int arg = 0;
  bool isbest = false;
#pragma unroll
  for (int j=0;j<8;j++) {
    const float o = ov[(size_t)n*8+j];
    if (o > best) { best = o; arg = j; }
    if (fkey(o) == gtmax[j]) isbest = true;
  }
  const bool inside = ov[(size_t)n*8+0] >= 0.f;
  int lab = -1;
  if (inside && best < 0.3f) lab = 0;
  if (inside && isbest) lab = 1;
  if (inside && best >= 0.7f) lab = 1;
  labels[n] = (signed char)lab;
  amax[n] = (signed char)arg;
  se[threadIdx.x] = (lab >= 0) ? 1 : 0;
  __syncthreads();
  for (int s=128; s>0; s>>=1) {
    if ((int)threadIdx.x < s) se[threadIdx.x] += se[threadIdx.x+s];
    __syncthreads();
  }
  if (threadIdx.x==0) exP[blockIdx.x] = se[0];
}

// ---------------- K13: per-anchor loss terms -> block partials ----------------
__global__ void loss_partial(const float* __restrict__ cls_out, const float* __restrict__ bbox_out,
                             const float* __restrict__ gt, const signed char* __restrict__ labels,
                             const signed char* __restrict__ amax, float2* __restrict__ lossP)
{
#pragma clang fp contract(off)
  __shared__ float sce[256];
  __shared__ float sbx[256];
  const int n = blockIdx.x*256 + threadIdx.x;
  const int hw = n/9, a = n - hw*9;
  const int lab = labels[n];
  float ce = 0.f, bx = 0.f;
  if (lab >= 0) {
    const float l0 = cls_out[a*HW+hw], l1 = cls_out[(9+a)*HW+hw];
    const float m = fmaxf(l0,l1);
    const float lse = m + logf(expf(l0-m)+expf(l1-m));
    ce = lse - (lab==1 ? l1 : l0);
  }
  if (lab == 1) {
    const int x = hw % HF, y = hw / HF;
    const float ax1 = BA[a][0]+16.f*(float)x, ay1 = BA[a][1]+16.f*(float)y;
    const float ax2 = BA[a][2]+16.f*(float)x, ay2 = BA[a][3]+16.f*(float)y;
    const float ew = ax2-ax1+1.f, eh = ay2-ay1+1.f;
    const float ecx = ax1+0.5f*ew, ecy = ay1+0.5f*eh;
    const int g = amax[n];
    const float g0=gt[g*5+0], g1=gt[g*5+1], g2=gt[g*5+2], g3=gt[g*5+3];
    const float gw = g2-g0+1.f, gh = g3-g1+1.f;
    const float gcx = g0+0.5f*gw, gcy = g1+0.5f*gh;
    float tgt[4];
    tgt[0] = (gcx-ecx)/ew;
    tgt[1] = (gcy-ecy)/eh;
    tgt[2] = logf(gw/ew);
    tgt[3] = logf(gh/eh);
#pragma unroll
    for (int j=0;j<4;j++) {
      const float d = bbox_out[(a*4+j)*HW+hw];
      const float diff = d - tgt[j];
      const float ad = fabsf(diff);
      bx += (ad < (1.0f/9.0f)) ? (4.5f*diff*diff) : (ad - 0.5f/9.0f);
    }
  }
  sce[threadIdx.x]=ce; sbx[threadIdx.x]=bx;
  __syncthreads();
  for (int s=128;s>0;s>>=1) {
    if ((int)threadIdx.x<s) { sce[threadIdx.x]+=sce[threadIdx.x+s]; sbx[threadIdx.x]+=sbx[threadIdx.x+s]; }
    __syncthreads();
  }
  if (threadIdx.x==0) lossP[blockIdx.x] = make_float2(sce[0], sbx[0]);
}

// ---------------- K14: final fixed-order reduction -> losses ----------------
__global__ void loss_final(const float2* __restrict__ lossP, const int* __restrict__ exP,
                           float* __restrict__ out)
{
  __shared__ float a[512];
  __shared__ float c[512];
  __shared__ int   e[512];
  const int t = threadIdx.x;
  float2 v = (t < NBLK) ? lossP[t] : make_float2(0.f,0.f);
  int ev = (t < NBLK) ? exP[t] : 0;
  a[t]=v.x; c[t]=v.y; e[t]=ev;
  __syncthreads();
  for (int s=256;s>0;s>>=1) {
    if (t<s) { a[t]+=a[t+s]; c[t]+=c[t+s]; e[t]+=e[t+s]; }
    __syncthreads();
  }
  if (t==0) {
    const float nex = (float)max(e[0], 1);
    out[OUT_POOL+0] = a[0] / nex;
    out[OUT_POOL+1] = c[0] / nex;
  }
}

// ---------------- launcher ----------------
extern "C" void kernel_launch(void* const* d_in, const int* in_sizes, int n_in,
                              void* d_out, int out_size, void* d_ws, size_t ws_size,
                              hipStream_t stream)
{
  const float* feat    = (const float*)d_in[0];
  const float* gt      = (const float*)d_in[1];
  const float* im_info = (const float*)d_in[2];
  const float* rpn_w   = (const float*)d_in[3];
  const float* rpn_b   = (const float*)d_in[4];
  const float* cls_w   = (const float*)d_in[5];
  const float* cls_b   = (const float*)d_in[6];
  const float* bbox_w  = (const float*)d_in[7];
  const float* bbox_b  = (const float*)d_in[8];
  float* out = (float*)d_out;
  char* ws = (char*)d_ws;

  size_t off = 0;
  auto alloc = [&](size_t bytes) {
    size_t o = off;
    off = (off + bytes + 255) & ~(size_t)255;
    return o;
  };
  // zero-region (memset every call)
  size_t o_counter = alloc(4);
  size_t o_gtmax   = alloc(32);
  size_t o_thresh  = alloc(4);
  size_t o_meta    = alloc(8);
  size_t o_h64     = alloc(256);
  size_t o_hist10  = alloc(1024*4);
  size_t zeroBytes = off;
  // persistent across phases
  size_t o_cls  = alloc((size_t)18*HW*4);
  size_t o_bbox = alloc((size_t)36*HW*4);
  size_t o_rpn  = alloc((size_t)CMID*HW*4);
  // overlapped region R
  size_t o_R = off;
  const size_t IMG_BYTES  = (size_t)32*98*98*8*16;   // 39,337,984
  const size_t WBUF_BYTES = (size_t)9*2*128*512*16;  // 18,874,368
  const size_t FEATT_BYTES= (size_t)HW*1024*4;       // 37,748,736
  size_t o_img  = o_R;
  size_t o_wbuf = o_R + ((IMG_BYTES + 255) & ~(size_t)255);
  // layout A (preferred): featT at o_R; phase B/C after featT
  size_t baseC_A = o_R + ((FEATT_BYTES + 255) & ~(size_t)255);
  auto phaseC = [&](size_t base, size_t* offs) {
    size_t co = base;
    auto ca = [&](size_t bytes) { size_t o = co; co = (co + bytes + 255) & ~(size_t)255; return o; };
    offs[0] = ca((size_t)4*54*HW*4);         // partial (phase B; dead before keys reused)
    co = base;                                // phase C overlays partial
    offs[1] = ca((size_t)NA*8);               // keys
    offs[2] = ca((size_t)NA*16);              // props
    offs[3] = ca((size_t)NA*8);               // cand
    offs[4] = ca((size_t)PRE*16);             // sprops
    offs[5] = ca((size_t)PRE*NW*8);           // mask
    offs[6] = ca((size_t)POST*5*4);           // rois
    offs[7] = ca((size_t)POST*49*sizeof(Samp)); // tab
    offs[8] = ca((size_t)NA*8*4);             // ov
    offs[9] = ca((size_t)NA);                 // labels
    offs[10]= ca((size_t)NA);                 // amax
    offs[11]= ca((size_t)NBLK*4);             // exP
    offs[12]= ca((size_t)NBLK*8);             // lossP
    size_t endC = co;
    co = base + (size_t)4*54*HW*4;            // partial end
    return endC > co ? endC : co;
  };
  size_t offsA[13], offsB[13];
  size_t endA = phaseC(baseC_A, offsA);
  size_t convEnd = o_wbuf + WBUF_BYTES;
  size_t neededA = (endA > convEnd ? endA : convEnd);
  size_t endB = phaseC(o_R, offsB);
  (void)endB;
  const bool useT = (ws_size >= neededA);
  const size_t* offs = useT ? offsA : offsB;
  (void)in_sizes; (void)n_in; (void)out_size;

  hipMemsetAsync(ws, 0, zeroBytes, stream);

  f16x8* img      = (f16x8*)(ws + o_img);
  f16x8* wbuf     = (f16x8*)(ws + o_wbuf);
  float* featT    = (float*)(ws + o_R);
  float* partial  = (float*)(ws + offs[0]);
  float* rpn      = (float*)(ws + o_rpn);
  float* cls_out  = (float*)(ws + o_cls);
  float* bbox_out = (float*)(ws + o_bbox);
  u64*   keys     = (u64*)(ws + offs[1]);
  float4* props   = (float4*)(ws + offs[2]);
  u64*   cand     = (u64*)(ws + offs[3]);
  float4* sprops  = (float4*)(ws + offs[4]);
  u64*   maskp    = (u64*)(ws + offs[5]);
  float* rois     = (float*)(ws + offs[6]);
  Samp*  tab      = (Samp*)(ws + offs[7]);
  float* ovp      = (float*)(ws + offs[8]);
  signed char* labels = (signed char*)(ws + offs[9]);
  signed char* amax   = (signed char*)(ws + offs[10]);
  int*    exP     = (int*)(ws + offs[11]);
  float2* lossP   = (float2*)(ws + offs[12]);
  u32* counter    = (u32*)(ws + o_counter);
  u32* gtmaxp     = (u32*)(ws + o_gtmax);
  u32* thresh     = (u32*)(ws + o_thresh);
  u32* metap      = (u32*)(ws + o_meta);
  u32* h64p       = (u32*)(ws + o_h64);
  u32* hist10     = (u32*)(ws + o_hist10);

  // phase A: conv via split-fp16 MFMA
  prep_img<<<dim3(98,32), 256, 0, stream>>>(feat, img);
  prep_w<<<256, 256, 0, stream>>>(rpn_w, wbuf);
  rpn_conv_mfma<<<dim3(2,96,4), 256, 0, stream>>>(img, wbuf, rpn_b, rpn);
  // phase B: 1x1 convs
  conv1x1p<<<dim3(144,4), 64, 0, stream>>>(rpn, cls_w, bbox_w, partial);
  conv1x1r<<<54*HW/256, 256, 0, stream>>>(partial, cls_b, bbox_b, cls_out, bbox_out);
  if (useT) transpose_feat<<<dim3(144,16), 256, 0, stream>>>(feat, featT);
  // phase C: proposals
  score_decode<<<NBLK, 256, 0, stream>>>(cls_out, bbox_out, im_info, keys, props, hist10);
  hist_scan1<<<1, 1024, 0, stream>>>(hist10, metap);
  hist_refine<<<NBLK, 256, 0, stream>>>(keys, metap, h64p);
  hist_scan2<<<1, 1, 0, stream>>>(h64p, metap, thresh);
  collect_cand<<<NBLK, 256, 0, stream>>>(keys, thresh, counter, cand);
  rank_scatter<<<NBLK, 256, 0, stream>>>(cand, counter, props, sprops);
  nms_mask<<<dim3(NW, NW), 64, 0, stream>>>(sprops, maskp);
  nms_scan<<<1, 64, 0, stream>>>(maskp, sprops, rois);
  roi_table<<<(POST*49+255)/256, 256, 0, stream>>>(rois, tab);
  if (useT) roi_pool_coal<<<dim3(POST,4), 256, 0, stream>>>(featT, tab, out);
  else      roi_pool_gather<<<OUT_POOL/256, 256, 0, stream>>>(feat, tab, out);
  // loss path
  anchor_ov<<<NBLK, 256, 0, stream>>>(gt, im_info, ovp, gtmaxp);
  anchor_label<<<NBLK, 256, 0, stream>>>(ovp, gtmaxp, labels, amax, exP);
  loss_partial<<<NBLK, 256, 0, stream>>>(cls_out, bbox_out, gt, labels, amax, lossP);
  loss_final<<<1, 512, 0, stream>>>(lossP, exP, out);
}

// Round 6
// 695.834 us; speedup vs baseline: 4.0368x; 1.2947x over previous
//
#include <hip/hip_runtime.h>
#include <stdint.h>

typedef unsigned int u32;
typedef unsigned long long u64;
typedef _Float16 f16x8 __attribute__((ext_vector_type(8)));
typedef float f32x4 __attribute__((ext_vector_type(4)));

#define HF 96
#define HW 9216           // 96*96
#define CIN 1024
#define CMID 512
#define NA 82944          // HW*9
#define PRE 12000
#define POST 300
#define NW 188            // ceil(PRE/64)
#define NBLK 324          // NA/256
#define OUT_POOL (POST*CIN*49)

// base anchors, exact per np.round (banker's) of the reference generator
__device__ __constant__ float BA[9][4] = {
  {-84.f,-40.f,99.f,55.f}, {-176.f,-88.f,191.f,103.f}, {-360.f,-184.f,375.f,199.f},
  {-56.f,-56.f,71.f,71.f}, {-120.f,-120.f,135.f,135.f}, {-248.f,-248.f,263.f,263.f},
  {-36.f,-80.f,51.f,95.f}, {-80.f,-168.f,95.f,183.f},  {-168.f,-344.f,183.f,359.f}
};

__device__ __forceinline__ u32 fkey(float f) {
  u32 u = __float_as_uint(f);
  return (u & 0x80000000u) ? ~u : (u | 0x80000000u);
}

__device__ __forceinline__ void gl_lds16(const void* g, void* l) {
  __builtin_amdgcn_global_load_lds((const __attribute__((address_space(1))) void*)g,
                                   (__attribute__((address_space(3))) void*)l, 16, 0, 0);
}

// ---------------- P1: feat -> swizzled fp16 hi/lo image with halo (coalesced) ----------------
__global__ void prep_img(const float* __restrict__ feat, f16x8* __restrict__ img)
{
  __shared__ float ls[32][100];
  const int yy = blockIdx.x;
  const int kt = blockIdx.y;
  const int tid = threadIdx.x;
  const int y = yy - 1;
  const bool yok = (unsigned)y < 96u;
  if (yok) {
    for (int e = tid; e < 3072; e += 256) {
      const int ci = e / 96;
      const int x = e - ci * 96;
      ls[ci][x] = feat[(size_t)(kt*32 + ci)*HW + y*96 + x];
    }
  }
  __syncthreads();
  for (int idx = tid; idx < 784; idx += 256) {
    const int col = idx >> 3;
    const int q = idx & 7;
    const int x = col - 1;
    f16x8 val;
#pragma unroll
    for (int i=0;i<8;i++) val[i] = (_Float16)0.f;
    if (yok && (unsigned)x < 96u) {
#pragma unroll
      for (int i=0;i<8;i++) {
        const float v = ls[(q&3)*8 + i][x];
        if (q < 4) val[i] = (_Float16)v;
        else { const _Float16 hi = (_Float16)v; val[i] = (_Float16)((v - (float)hi)*1024.f); }
      }
    }
    const int sw = (col + 2*y) & 7;
    img[(size_t)((kt*98 + yy)*98 + col)*8 + (q ^ sw)] = val;
  }
}

// ---------------- P2: weights -> frag-ready hi/lo (x64 pre-scale), kt-major ----------------
__global__ void prep_w(const float* __restrict__ w, f16x8* __restrict__ wbuf)
{
  const int t = blockIdx.x*256 + threadIdx.x;   // 65536 total
  const int co = t & 511;
  const int cic = t >> 9;                        // 0..127
  const int kt = cic >> 2;
  const int kg = cic & 3;
  const float* wp = w + (size_t)co*9216 + cic*72;
#pragma unroll
  for (int tap=0; tap<9; ++tap) {
    f16x8 hv, lv;
#pragma unroll
    for (int i=0;i<8;i++) {
      const float v = wp[i*9 + tap] * 64.f;
      const _Float16 hi = (_Float16)v;
      hv[i] = hi;
      lv[i] = (_Float16)((v - (float)hi)*1024.f);
    }
    wbuf[(size_t)(((kt*9 + tap)*2 + 0)*4 + kg)*512 + co] = hv;
    wbuf[(size_t)(((kt*9 + tap)*2 + 1)*4 + kg)*512 + co] = lv;
  }
}

// ---------------- K1: 3x3 conv, 2-wave blocks, co_t=4, double-buffered ----------------
// block 128 thr (2 waves); tile 128co x 48px; grid (2,96,4)=768 = 3 blocks/CU.
__global__ __launch_bounds__(128, 2) void rpn_conv_mfma(
    const f16x8* __restrict__ img, const f16x8* __restrict__ wbuf,
    const float* __restrict__ bias, float* __restrict__ out)
{
  __shared__ f16x8 in_s[2560];   // 2 buffers x 1280 slots x 16B
  const int tid = threadIdx.x;
  const int lane = tid & 63;
  const int wv = tid >> 6;        // 0..1
  const int kgrp = lane >> 4;
  const int ln15 = lane & 15;
  const int x0 = blockIdx.x * 48;
  const int y  = blockIdx.y;
  const int co0 = blockIdx.z * 128 + wv * 64;

  int goff[10];
#pragma unroll
  for (int j=0;j<10;j++) {
    int s = j*128 + tid; if (s > 1199) s = 1199;
    const int row = s / 400;
    const int rem = s - row*400;
    goff[j] = ((y + row)*98 + x0 + (rem>>3))*8 + (rem & 7);
  }
  const int ldst0 = wv*64;

  int keyb[3];
#pragma unroll
  for (int pt=0; pt<3; ++pt) keyb[pt] = x0 + pt*16 + ln15 + 1 + 2*y;

  f32x4 acc1[4][3], acc2[4][3];
#pragma unroll
  for (int c=0;c<4;c++)
#pragma unroll
    for (int pt=0;pt<3;pt++) {
      acc1[c][pt] = (f32x4){0.f,0.f,0.f,0.f};
      acc2[c][pt] = (f32x4){0.f,0.f,0.f,0.f};
    }

  const int wlane = kgrp*512 + co0 + ln15;

  // prologue: stage kt=0 into buffer 0
#pragma unroll
  for (int j=0;j<10;j++) gl_lds16(img + goff[j], in_s + j*128 + ldst0);
  asm volatile("s_waitcnt vmcnt(0)" ::: "memory");
  __syncthreads();

  for (int kt = 0; kt < 32; ++kt) {
    const int cur = (kt & 1) * 1280;
    if (kt < 31) {
      const f16x8* kb = img + (size_t)(kt+1)*76832;
#pragma unroll
      for (int j=0;j<10;j++) gl_lds16(kb + goff[j], in_s + (1280 - cur) + j*128 + ldst0);
    }
    const f16x8* bs = in_s + cur;
#pragma unroll
    for (int t=0; t<9; ++t) {
      const int dy = t/3 - 1, dx = t%3 - 1;
      f16x8 af[4][2];
#pragma unroll
      for (int h=0;h<2;h++) {
        const size_t wb = (size_t)(((kt*9 + t)*2 + h)*2048) + wlane;
#pragma unroll
        for (int c=0;c<4;c++) af[c][h] = wbuf[wb + c*16];
      }
      f16x8 bf[3][2];
#pragma unroll
      for (int pt=0;pt<3;pt++) {
        const int key = (keyb[pt] + dx + 2*dy) & 7;
        const int base = ((dy+1)*50 + pt*16 + ln15 + dx + 1)*8;
#pragma unroll
        for (int h=0;h<2;h++)
          bf[pt][h] = bs[base + ((h*4 + kgrp) ^ key)];
      }
#pragma unroll
      for (int c=0;c<4;c++)
#pragma unroll
        for (int pt=0;pt<3;pt++) {
          acc1[c][pt] = __builtin_amdgcn_mfma_f32_16x16x32_f16(af[c][0], bf[pt][0], acc1[c][pt], 0,0,0);
          acc2[c][pt] = __builtin_amdgcn_mfma_f32_16x16x32_f16(af[c][0], bf[pt][1], acc2[c][pt], 0,0,0);
          acc2[c][pt] = __builtin_amdgcn_mfma_f32_16x16x32_f16(af[c][1], bf[pt][0], acc2[c][pt], 0,0,0);
        }
    }
    asm volatile("s_waitcnt vmcnt(0)" ::: "memory");
    __syncthreads();
  }

  const int pixb = y*96 + x0;
#pragma unroll
  for (int c=0;c<4;c++) {
#pragma unroll
    for (int i=0;i<4;i++) {
      const int co = co0 + c*16 + kgrp*4 + i;
      const float bb = bias[co];
#pragma unroll
      for (int pt=0;pt<3;pt++) {
        const float v = (acc1[c][pt][i] + acc2[c][pt][i]*(1.f/1024.f))*(1.f/64.f) + bb;
        out[(size_t)co*HW + pixb + pt*16 + ln15] = v > 0.f ? v : 0.f;
      }
    }
  }
}

// ---------------- K2: 1x1 convs — 8-way ci-split partials + deterministic reduce ----------------
__global__ void conv1x1p(const float* __restrict__ rpn,
    const float* __restrict__ cw, const float* __restrict__ bw,
    float* __restrict__ partial)
{
  const int hw = blockIdx.x * 256 + threadIdx.x;
  const int cg = blockIdx.y;           // 0..7
  const int ci0 = cg * 64;
  float accA[18], accB[36];
#pragma unroll
  for (int c=0;c<18;c++) accA[c]=0.f;
#pragma unroll
  for (int c=0;c<36;c++) accB[c]=0.f;
  for (int ci=ci0; ci<ci0+64; ++ci) {
    const float v = rpn[(size_t)ci*HW + hw];
#pragma unroll
    for (int c=0;c<18;c++) accA[c] = fmaf(v, cw[c*CMID+ci], accA[c]);
#pragma unroll
    for (int c=0;c<36;c++) accB[c] = fmaf(v, bw[c*CMID+ci], accB[c]);
  }
  float* p = partial + (size_t)cg*54*HW;
#pragma unroll
  for (int c=0;c<18;c++) p[(size_t)c*HW + hw] = accA[c];
#pragma unroll
  for (int c=0;c<36;c++) p[(size_t)(18+c)*HW + hw] = accB[c];
}

__global__ void conv1x1r(const float* __restrict__ partial,
    const float* __restrict__ cb, const float* __restrict__ bb,
    float* __restrict__ cls_out, float* __restrict__ bbox_out)
{
  const int o = blockIdx.x*256 + threadIdx.x;    // 54*HW total
  const int c = o / HW;
  const int hw = o - c*HW;
  float v = partial[o];
#pragma unroll
  for (int g=1; g<8; ++g) v += partial[(size_t)g*54*HW + o];
  if (c < 18) cls_out[(size_t)c*HW + hw] = v + cb[c];
  else        bbox_out[(size_t)(c-18)*HW + hw] = v + bb[c-18];
}

// ---------------- K3: scores+keys+hist + decode+clip + anchor_ov (fused) ----------------
__global__ void score_decode_ov(const float* __restrict__ cls_out,
    const float* __restrict__ bbox_out, const float* __restrict__ im_info,
    const float* __restrict__ gt,
    u64* __restrict__ keys, float4* __restrict__ props, u32* __restrict__ hist10,
    float* __restrict__ ov, u32* __restrict__ gtmax)
{
#pragma clang fp contract(off)
  __shared__ u32 h[1024];
  __shared__ u32 lmax[8];
  const int tid = threadIdx.x;
  for (int i=tid;i<1024;i+=256) h[i]=0;
  if (tid < 8) lmax[tid] = 0u;
  __syncthreads();
  const int n = blockIdx.x*256 + tid;
  const int hw = n / 9;
  const int a  = n - hw*9;
  const int x = hw % HF, y = hw / HF;
  const float l0 = cls_out[a*HW + hw];
  const float l1 = cls_out[(9+a)*HW + hw];
  const float m = fmaxf(l0, l1);
  const float e0 = expf(l0 - m), e1 = expf(l1 - m);
  const float s = e1 / (e0 + e1);
  const u32 sb = __float_as_uint(s);      // s >= 0 -> bits monotone
  keys[n] = ((u64)(~sb) << 32) | (u32)n;  // asc key == desc score, tie -> asc idx
  atomicAdd(&h[sb >> 22], 1u);

  const float ax1 = BA[a][0] + 16.f*(float)x;
  const float ay1 = BA[a][1] + 16.f*(float)y;
  const float ax2 = BA[a][2] + 16.f*(float)x;
  const float ay2 = BA[a][3] + 16.f*(float)y;
  const float aw = ax2 - ax1 + 1.f, ah = ay2 - ay1 + 1.f;
  const float cx = ax1 + 0.5f*aw,  cy = ay1 + 0.5f*ah;
  const float d0 = bbox_out[(a*4+0)*HW + hw];
  const float d1 = bbox_out[(a*4+1)*HW + hw];
  const float d2 = bbox_out[(a*4+2)*HW + hw];
  const float d3 = bbox_out[(a*4+3)*HW + hw];
  const float pcx = d0*aw + cx, pcy = d1*ah + cy;
  const float pw = expf(d2)*aw, ph = expf(d3)*ah;
  const float imh = im_info[0], imw = im_info[1];
  float bx1 = fminf(fmaxf(pcx - 0.5f*pw, 0.f), imw - 1.f);
  float by1 = fminf(fmaxf(pcy - 0.5f*ph, 0.f), imh - 1.f);
  float bx2 = fminf(fmaxf(pcx + 0.5f*pw, 0.f), imw - 1.f);
  float by2 = fminf(fmaxf(pcy + 0.5f*ph, 0.f), imh - 1.f);
  props[n] = make_float4(bx1, by1, bx2, by2);

  // anchor_ov part (independent)
  const bool inside = (ax1 >= 0.f) && (ay1 >= 0.f) && (ax2 < imw) && (ay2 < imh);
  const float aa = aw * ah;
#pragma unroll
  for (int j=0;j<8;j++) {
    const float g0=gt[j*5+0], g1=gt[j*5+1], g2=gt[j*5+2], g3=gt[j*5+3];
    const float ga = (g2-g0+1.f)*(g3-g1+1.f);
    const float xx1 = fmaxf(ax1,g0), yy1 = fmaxf(ay1,g1);
    const float xx2 = fminf(ax2,g2), yy2 = fminf(ay2,g3);
    const float inter = fmaxf(xx2-xx1+1.f,0.f)*fmaxf(yy2-yy1+1.f,0.f);
    const float iou = inter/(aa+ga-inter);
    const float o = inside ? iou : -1.f;
    ov[(size_t)n*8+j] = o;
    atomicMax(&lmax[j], fkey(o));
  }
  __syncthreads();
  for (int i=tid;i<1024;i+=256) if (h[i]) atomicAdd(&hist10[i], h[i]);
  if (tid < 8) atomicMax(&gtmax[tid], lmax[tid]);
}

// ---------------- K4a: coarse threshold bucket ----------------
__global__ void hist_scan1(const u32* __restrict__ hist10, u32* __restrict__ meta)
{
  __shared__ u32 c[1024];
  const int t = threadIdx.x;
  c[t] = hist10[t];
  __syncthreads();
  if (t == 0) {
    u32 cum = 0;
    int b = 1023;
    for (; b > 0; --b) {
      if (cum + c[b] >= PRE) break;
      cum += c[b];
    }
    meta[0] = (u32)b;
    meta[1] = cum;
  }
}

// ---------------- K4b: refine hist + anchor labels (fused) ----------------
__global__ void refine_label(const u64* __restrict__ keys, const u32* __restrict__ meta,
                             u32* __restrict__ h64,
                             const float* __restrict__ ov, const u32* __restrict__ gtmax,
                             signed char* __restrict__ labels, signed char* __restrict__ amax,
                             int* __restrict__ exP)
{
  __shared__ u32 h[64];
  __shared__ int se[256];
  const int tid = threadIdx.x;
  if (tid < 64) h[tid] = 0;
  __syncthreads();
  const int n = blockIdx.x*256 + tid;
  const u32 sb = ~(u32)(keys[n] >> 32);
  if ((sb >> 22) == meta[0]) atomicAdd(&h[(sb >> 16) & 63], 1u);

  float best = -3.402823466e38f;
  int arg = 0;
  bool isbest = false;
#pragma unroll
  for (int j=0;j<8;j++) {
    const float o = ov[(size_t)n*8+j];
    if (o > best) { best = o; arg = j; }
    if (fkey(o) == gtmax[j]) isbest = true;
  }
  const bool inside = ov[(size_t)n*8+0] >= 0.f;
  int lab = -1;
  if (inside && best < 0.3f) lab = 0;
  if (inside && isbest) lab = 1;
  if (inside && best >= 0.7f) lab = 1;
  labels[n] = (signed char)lab;
  amax[n] = (signed char)arg;
  se[tid] = (lab >= 0) ? 1 : 0;
  __syncthreads();
  if (tid < 64 && h[tid]) atomicAdd(&h64[tid], h[tid]);
  for (int s=128; s>0; s>>=1) {
    if (tid < s) se[tid] += se[tid+s];
    __syncthreads();
  }
  if (tid==0) exP[blockIdx.x] = se[0];
}

// ---------------- K4c: exact 16-bit threshold ----------------
__global__ void hist_scan2(const u32* __restrict__ h64, const u32* __restrict__ meta,
                           u32* __restrict__ thresh)
{
  u32 cum = meta[1];
  int s = 63;
  for (; s > 0; --s) { cum += h64[s]; if (cum >= PRE) break; }
  if (s == 0) cum += h64[0];
  thresh[0] = (meta[0] << 6) | (u32)s;
}

// ---------------- K5: compact candidates + per-anchor loss partials (fused) ----------------
__global__ void collect_loss(const u64* __restrict__ keys, const u32* __restrict__ thresh,
                             u32* __restrict__ counter, u64* __restrict__ cand,
                             const float* __restrict__ cls_out, const float* __restrict__ bbox_out,
                             const float* __restrict__ gt, const signed char* __restrict__ labels,
                             const signed char* __restrict__ amax, float2* __restrict__ lossP)
{
#pragma clang fp contract(off)
  __shared__ float sce[256];
  __shared__ float sbx[256];
  const int tid = threadIdx.x;
  const int n = blockIdx.x*256 + tid;
  const u64 k = keys[n];
  const u32 sb = ~(u32)(k >> 32);
  if ((sb >> 16) >= thresh[0]) {
    u32 p = atomicAdd(counter, 1u);
    cand[p] = k;
  }
  const int hw = n/9, a = n - hw*9;
  const int lab = labels[n];
  float ce = 0.f, bx = 0.f;
  if (lab >= 0) {
    const float l0 = cls_out[a*HW+hw], l1 = cls_out[(9+a)*HW+hw];
    const float m = fmaxf(l0,l1);
    const float lse = m + logf(expf(l0-m)+expf(l1-m));
    ce = lse - (lab==1 ? l1 : l0);
  }
  if (lab == 1) {
    const int x = hw % HF, y = hw / HF;
    const float ax1 = BA[a][0]+16.f*(float)x, ay1 = BA[a][1]+16.f*(float)y;
    const float ax2 = BA[a][2]+16.f*(float)x, ay2 = BA[a][3]+16.f*(float)y;
    const float ew = ax2-ax1+1.f, eh = ay2-ay1+1.f;
    const float ecx = ax1+0.5f*ew, ecy = ay1+0.5f*eh;
    const int g = amax[n];
    const float g0=gt[g*5+0], g1=gt[g*5+1], g2=gt[g*5+2], g3=gt[g*5+3];
    const float gw = g2-g0+1.f, gh = g3-g1+1.f;
    const float gcx = g0+0.5f*gw, gcy = g1+0.5f*gh;
    float tgt[4];
    tgt[0] = (gcx-ecx)/ew;
    tgt[1] = (gcy-ecy)/eh;
    tgt[2] = logf(gw/ew);
    tgt[3] = logf(gh/eh);
#pragma unroll
    for (int j=0;j<4;j++) {
      const float d = bbox_out[(a*4+j)*HW+hw];
      const float diff = d - tgt[j];
      const float ad = fabsf(diff);
      bx += (ad < (1.0f/9.0f)) ? (4.5f*diff*diff) : (ad - 0.5f/9.0f);
    }
  }
  sce[tid]=ce; sbx[tid]=bx;
  __syncthreads();
  for (int s=128;s>0;s>>=1) {
    if (tid<s) { sce[tid]+=sce[tid+s]; sbx[tid]+=sbx[tid+s]; }
    __syncthreads();
  }
  if (tid==0) lossP[blockIdx.x] = make_float2(sce[0], sbx[0]);
}

// ---------------- K6a: partial ranks (j-parallel) ----------------
__global__ void rank_partial(const u64* __restrict__ cand, const u32* __restrict__ counter,
                             u32* __restrict__ rankbuf)
{
  __shared__ u64 sk[256];
  const int M = (int)counter[0];
  if (blockIdx.x*256 >= M) return;
  const int i = blockIdx.x*256 + threadIdx.x;
  const u64 key = (i < M) ? cand[i] : ~0ull;
  const int chunk = ((M + 7)/8 + 255) & ~255;
  const int j0 = blockIdx.y*chunk;
  const int j1 = (j0 + chunk < M) ? (j0 + chunk) : M;
  int rank = 0;
  for (int t0 = j0; t0 < j1; t0 += 256) {
    const int j = t0 + threadIdx.x;
    sk[threadIdx.x] = (j < M) ? cand[j] : ~0ull;
    __syncthreads();
    const int lim = (j1 - t0 < 256) ? (j1 - t0) : 256;
    for (int k=0;k<lim;k++) rank += (sk[k] < key) ? 1 : 0;
    __syncthreads();
  }
  if (i < M && rank) atomicAdd(&rankbuf[i], (u32)rank);
}

// ---------------- K6b: scatter by rank ----------------
__global__ void rank_scatter2(const u64* __restrict__ cand, const u32* __restrict__ counter,
                              const u32* __restrict__ rankbuf, const float4* __restrict__ props,
                              float4* __restrict__ sprops)
{
  const int M = (int)counter[0];
  const int i = blockIdx.x*256 + threadIdx.x;
  if (i >= M) return;
  const u32 r = rankbuf[i];
  if (r < PRE) sprops[r] = props[(u32)cand[i]];
}

// ---------------- K7: NMS suppression bitmask (upper triangle only) ----------------
__global__ void nms_mask(const float4* __restrict__ sp, u64* __restrict__ mask)
{
#pragma clang fp contract(off)
  if (blockIdx.x*64 + 63 < blockIdx.y*64) return;
  __shared__ float4 cb[64];
  __shared__ float  ca[64];
  const int c0 = blockIdx.x * 64;
  const int cend = min(64, PRE - c0);
  if ((int)threadIdx.x < cend) {
    float4 b = sp[c0 + threadIdx.x];
    cb[threadIdx.x] = b;
    ca[threadIdx.x] = (b.z-b.x+1.f)*(b.w-b.y+1.f);
  }
  __syncthreads();
  const int row = blockIdx.y*64 + threadIdx.x;
  if (row >= PRE) return;
  const float4 rb = sp[row];
  const float ra = (rb.z-rb.x+1.f)*(rb.w-rb.y+1.f);
  u64 bits = 0;
  for (int j=0;j<cend;j++) {
    const float4 c = cb[j];
    const float xx1 = fmaxf(rb.x, c.x), yy1 = fmaxf(rb.y, c.y);
    const float xx2 = fminf(rb.z, c.z), yy2 = fminf(rb.w, c.w);
    const float inter = fmaxf(xx2-xx1+1.f, 0.f) * fmaxf(yy2-yy1+1.f, 0.f);
    const float iou = inter / (ra + ca[j] - inter);
    if (iou > 0.7f) bits |= (1ull << j);
  }
  mask[(size_t)row*NW + blockIdx.x] = bits;
}

// ---------------- K8: fused {serial NMS scan | loss_final | feat transpose} ----------------
__global__ void fused_scan_tr(const u64* __restrict__ mask, const float4* __restrict__ sp,
                              float* __restrict__ rois,
                              const float2* __restrict__ lossP, const int* __restrict__ exP,
                              float* __restrict__ out,
                              const float* __restrict__ feat, float* __restrict__ featT, int doT)
{
  const int b = blockIdx.x;
  if (b == 0) {
    __shared__ int keep_s[POST];
    if (threadIdx.x < 64) {
      const int l = threadIdx.x;
      u64 v[4];
#pragma unroll
      for (int q=0;q<4;q++) {
        const int w = l*4+q;
        u64 val = 0;
        if (w < NW) { val = ~0ull; if (w == NW-1) val = (1ull<<32) - 1ull; }
        v[q] = val;
      }
      for (int it=0; it<POST; ++it) {
        const u64 nz = (v[0]|v[1]) | (v[2]|v[3]);
        const u64 bal = __ballot(nz != 0);
        int idx = -1;
        if (bal != 0) {
          const int src = __ffsll((unsigned long long)bal) - 1;
          int fi = 0;
          if (v[0])      fi = (l*4+0)*64 + __ffsll(v[0]) - 1;
          else if (v[1]) fi = (l*4+1)*64 + __ffsll(v[1]) - 1;
          else if (v[2]) fi = (l*4+2)*64 + __ffsll(v[2]) - 1;
          else if (v[3]) fi = (l*4+3)*64 + __ffsll(v[3]) - 1;
          idx = __shfl(fi, src);
        }
        if (l == 0) keep_s[it] = (idx < 0) ? 0 : idx;
        if (idx >= 0 && nz != 0) {
          const u64* mrow = mask + (size_t)idx*NW + l*4;
          v[0] &= ~mrow[0]; v[1] &= ~mrow[1]; v[2] &= ~mrow[2]; v[3] &= ~mrow[3];
        }
      }
    }
    __syncthreads();
    for (int i = threadIdx.x; i < POST; i += 256) {
      const float4 bb = sp[keep_s[i]];
      rois[i*5+0] = 0.f;
      rois[i*5+1] = bb.x; rois[i*5+2] = bb.y; rois[i*5+3] = bb.z; rois[i*5+4] = bb.w;
    }
  } else if (b == 1) {
    __shared__ float a[256];
    __shared__ float c[256];
    __shared__ int   e[256];
    const int t = threadIdx.x;
    float ax = 0.f, cx = 0.f; int ev = 0;
    if (t < NBLK) { float2 v = lossP[t]; ax = v.x; cx = v.y; ev = exP[t]; }
    if (t + 256 < NBLK) { float2 v = lossP[t+256]; ax += v.x; cx += v.y; ev += exP[t+256]; }
    a[t]=ax; c[t]=cx; e[t]=ev;
    __syncthreads();
    for (int s=128;s>0;s>>=1) {
      if (t<s) { a[t]+=a[t+s]; c[t]+=c[t+s]; e[t]+=e[t+s]; }
      __syncthreads();
    }
    if (t==0) {
      const float nex = (float)max(e[0], 1);
      out[OUT_POOL+0] = a[0] / nex;
      out[OUT_POOL+1] = c[0] / nex;
    }
  } else if (doT) {
    __shared__ float t[64][65];
    const int tt = b - 2;               // 0..2303
    const int bxhw = (tt % 144)*64, byc = (tt / 144)*64;
    const int tid = threadIdx.x;
    const int l = tid & 63, g = tid >> 6;
#pragma unroll
    for (int i=0;i<16;i++) {
      const int cL = g + 4*i;
      t[cL][l] = feat[(size_t)(byc+cL)*HW + bxhw + l];
    }
    __syncthreads();
#pragma unroll
    for (int i=0;i<16;i++) {
      const int hwL = g + 4*i;
      featT[(size_t)(bxhw+hwL)*1024 + byc + l] = t[l][hwL];
    }
  }
}

// ---------------- K9: ROI bilinear crop ----------------
struct __align__(16) Samp { int p0,p1,p2,p3; float w0,w1,w2,w3; };

__device__ __forceinline__ Samp make_samp(const float* __restrict__ rois, int r, int s)
{
#pragma clang fp contract(off)
  const int py = s / 7, px = s - py*7;
  const float x1 = rois[r*5+1] * 0.0625f;
  const float y1 = rois[r*5+2] * 0.0625f;
  const float x2 = rois[r*5+3] * 0.0625f;
  const float y2 = rois[r*5+4] * 0.0625f;
  const float t00 = (x2-x1)/95.f;
  const float t02 = (x1+x2-95.f)/95.f;
  const float t11 = (y2-y1)/95.f;
  const float t12 = (y1+y2-95.f)/95.f;
  const float lx = (float)(px-3)/3.f;
  const float ly = (float)(py-3)/3.f;
  const float gx = t00*lx + t02;
  const float gy = t11*ly + t12;
  const float ix = (gx+1.f)*0.5f*95.f;
  const float iy = (gy+1.f)*0.5f*95.f;
  const float ix0 = floorf(ix), iy0 = floorf(iy);
  const float wx = ix-ix0, wy = iy-iy0;
  const float xs[2] = {ix0, ix0+1.f};
  const float ys[2] = {iy0, iy0+1.f};
  const float wxs[2] = {1.f-wx, wx};
  const float wys[2] = {1.f-wy, wy};
  int pos[4]; float wt[4];
#pragma unroll
  for (int k=0;k<4;k++) {
    const int dy = k>>1, dx = k&1;
    const float yi = ys[dy], xi = xs[dx];
    const bool valid = (yi>=0.f)&&(yi<96.f)&&(xi>=0.f)&&(xi<96.f);
    const int yc = (int)fminf(fmaxf(yi,0.f),95.f);
    const int xc = (int)fminf(fmaxf(xi,0.f),95.f);
    pos[k] = yc*96+xc;
    wt[k] = wys[dy]*wxs[dx] * (valid?1.f:0.f);
  }
  Samp t;
  t.p0=pos[0]; t.p1=pos[1]; t.p2=pos[2]; t.p3=pos[3];
  t.w0=wt[0];  t.w1=wt[1];  t.w2=wt[2];  t.w3=wt[3];
  return t;
}

__global__ void roi_pool_coal(const float* __restrict__ featT, const float* __restrict__ rois,
                              float* __restrict__ out)
{
#pragma clang fp contract(off)
  __shared__ float st[49][257];
  __shared__ Samp sam[49];
  const int tid = threadIdx.x;
  const int r = blockIdx.x, cb = blockIdx.y;
  if (tid < 49) sam[tid] = make_samp(rois, r, tid);
  __syncthreads();
  const int c = cb*256 + tid;
  for (int s=0;s<49;s++) {
    const Samp t = sam[s];
    st[s][tid] = t.w0*featT[(size_t)t.p0*1024+c] + t.w1*featT[(size_t)t.p1*1024+c]
               + t.w2*featT[(size_t)t.p2*1024+c] + t.w3*featT[(size_t)t.p3*1024+c];
  }
  __syncthreads();
  float* ob = out + (size_t)r*50176 + cb*12544;
  for (int i=tid; i<12544; i+=256) {
    const int cL = i / 49, s = i - cL*49;
    ob[i] = st[s][cL];
  }
}

__global__ void roi_pool_gather(const float* __restrict__ feat, const float* __restrict__ rois,
                                float* __restrict__ out)
{
#pragma clang fp contract(off)
  const int o = blockIdx.x*256 + threadIdx.x;
  const int s  = o % 49;
  const int rc = o / 49;
  const int c = rc & (CIN-1);
  const int r = rc >> 10;
  const Samp t = make_samp(rois, r, s);
  const float* f = feat + (size_t)c*HW;
  out[o] = t.w0*f[t.p0] + t.w1*f[t.p1] + t.w2*f[t.p2] + t.w3*f[t.p3];
}

// ---------------- launcher ----------------
extern "C" void kernel_launch(void* const* d_in, const int* in_sizes, int n_in,
                              void* d_out, int out_size, void* d_ws, size_t ws_size,
                              hipStream_t stream)
{
  const float* feat    = (const float*)d_in[0];
  const float* gt      = (const float*)d_in[1];
  const float* im_info = (const float*)d_in[2];
  const float* rpn_w   = (const float*)d_in[3];
  const float* rpn_b   = (const float*)d_in[4];
  const float* cls_w   = (const float*)d_in[5];
  const float* cls_b   = (const float*)d_in[6];
  const float* bbox_w  = (const float*)d_in[7];
  const float* bbox_b  = (const float*)d_in[8];
  float* out = (float*)d_out;
  char* ws = (char*)d_ws;

  size_t off = 0;
  auto alloc = [&](size_t bytes) {
    size_t o = off;
    off = (off + bytes + 255) & ~(size_t)255;
    return o;
  };
  // zero-region (memset every call)
  size_t o_counter = alloc(4);
  size_t o_gtmax   = alloc(32);
  size_t o_thresh  = alloc(4);
  size_t o_meta    = alloc(8);
  size_t o_h64     = alloc(256);
  size_t o_hist10  = alloc(1024*4);
  size_t o_rank    = alloc((size_t)NA*4);
  size_t zeroBytes = off;
  // persistent across phases
  size_t o_cls  = alloc((size_t)18*HW*4);
  size_t o_bbox = alloc((size_t)36*HW*4);
  size_t o_rpn  = alloc((size_t)CMID*HW*4);
  // overlapped region R
  size_t o_R = off;
  const size_t IMG_BYTES  = (size_t)32*98*98*8*16;   // 39,337,984
  const size_t WBUF_BYTES = (size_t)9*2*128*512*16;  // 18,874,368
  const size_t FEATT_BYTES= (size_t)HW*1024*4;       // 37,748,736
  size_t o_img  = o_R;
  size_t o_wbuf = o_R + ((IMG_BYTES + 255) & ~(size_t)255);
  size_t baseC_A = o_R + ((FEATT_BYTES + 255) & ~(size_t)255);
  auto phaseC = [&](size_t base, size_t* offs) {
    size_t co = base;
    auto ca = [&](size_t bytes) { size_t o = co; co = (co + bytes + 255) & ~(size_t)255; return o; };
    offs[0] = ca((size_t)8*54*HW*4);          // partial (phase B)
    co = base;                                // phase C overlays partial
    offs[1] = ca((size_t)NA*8);               // keys
    offs[2] = ca((size_t)NA*16);              // props
    offs[3] = ca((size_t)NA*8);               // cand
    offs[4] = ca((size_t)PRE*16);             // sprops
    offs[5] = ca((size_t)PRE*NW*8);           // mask
    offs[6] = ca((size_t)POST*5*4);           // rois
    offs[7] = ca((size_t)NA*8*4);             // ov
    offs[8] = ca((size_t)NA);                 // labels
    offs[9] = ca((size_t)NA);                 // amax
    offs[10]= ca((size_t)NBLK*4);             // exP
    offs[11]= ca((size_t)NBLK*8);             // lossP
    size_t endC = co;
    size_t endB = base + (size_t)8*54*HW*4;
    return endC > endB ? endC : endB;
  };
  size_t offsA[12], offsB[12];
  size_t endA = phaseC(baseC_A, offsA);
  size_t convEnd = o_wbuf + WBUF_BYTES;
  size_t neededA = (endA > convEnd ? endA : convEnd);
  size_t endB = phaseC(o_R, offsB);
  (void)endB;
  const bool useT = (ws_size >= neededA);
  const size_t* offs = useT ? offsA : offsB;
  (void)in_sizes; (void)n_in; (void)out_size;

  hipMemsetAsync(ws, 0, zeroBytes, stream);

  f16x8* img      = (f16x8*)(ws + o_img);
  f16x8* wbuf     = (f16x8*)(ws + o_wbuf);
  float* featT    = (float*)(ws + o_R);
  float* partial  = (float*)(ws + offs[0]);
  float* rpn      = (float*)(ws + o_rpn);
  float* cls_out  = (float*)(ws + o_cls);
  float* bbox_out = (float*)(ws + o_bbox);
  u64*   keys     = (u64*)(ws + offs[1]);
  float4* props   = (float4*)(ws + offs[2]);
  u64*   cand     = (u64*)(ws + offs[3]);
  float4* sprops  = (float4*)(ws + offs[4]);
  u64*   maskp    = (u64*)(ws + offs[5]);
  float* rois     = (float*)(ws + offs[6]);
  float* ovp      = (float*)(ws + offs[7]);
  signed char* labels = (signed char*)(ws + offs[8]);
  signed char* amax   = (signed char*)(ws + offs[9]);
  int*    exP     = (int*)(ws + offs[10]);
  float2* lossP   = (float2*)(ws + offs[11]);
  u32* counter    = (u32*)(ws + o_counter);
  u32* gtmaxp     = (u32*)(ws + o_gtmax);
  u32* thresh     = (u32*)(ws + o_thresh);
  u32* metap      = (u32*)(ws + o_meta);
  u32* h64p       = (u32*)(ws + o_h64);
  u32* hist10     = (u32*)(ws + o_hist10);
  u32* rankbuf    = (u32*)(ws + o_rank);

  // phase A: conv via split-fp16 MFMA
  prep_img<<<dim3(98,32), 256, 0, stream>>>(feat, img);
  prep_w<<<256, 256, 0, stream>>>(rpn_w, wbuf);
  rpn_conv_mfma<<<dim3(2,96,4), 128, 0, stream>>>(img, wbuf, rpn_b, rpn);
  // phase B: 1x1 convs
  conv1x1p<<<dim3(36,8), 256, 0, stream>>>(rpn, cls_w, bbox_w, partial);
  conv1x1r<<<54*HW/256, 256, 0, stream>>>(partial, cls_b, bbox_b, cls_out, bbox_out);
  // phase C: proposals + anchor targets
  score_decode_ov<<<NBLK, 256, 0, stream>>>(cls_out, bbox_out, im_info, gt,
                                            keys, props, hist10, ovp, gtmaxp);
  hist_scan1<<<1, 1024, 0, stream>>>(hist10, metap);
  refine_label<<<NBLK, 256, 0, stream>>>(keys, metap, h64p, ovp, gtmaxp, labels, amax, exP);
  hist_scan2<<<1, 1, 0, stream>>>(h64p, metap, thresh);
  collect_loss<<<NBLK, 256, 0, stream>>>(keys, thresh, counter, cand,
                                         cls_out, bbox_out, gt, labels, amax, lossP);
  rank_partial<<<dim3(NBLK,8), 256, 0, stream>>>(cand, counter, rankbuf);
  rank_scatter2<<<NBLK, 256, 0, stream>>>(cand, counter, rankbuf, props, sprops);
  nms_mask<<<dim3(NW, NW), 64, 0, stream>>>(sprops, maskp);
  fused_scan_tr<<<2306, 256, 0, stream>>>(maskp, sprops, rois, lossP, exP, out,
                                          feat, featT, useT ? 1 : 0);
  if (useT) roi_pool_coal<<<dim3(POST,4), 256, 0, stream>>>(featT, rois, out);
  else      roi_pool_gather<<<OUT_POOL/256, 256, 0, stream>>>(feat, rois, out);
}